// Round 1
// baseline (946.595 us; speedup 1.0000x reference)
//
#include <hip/hip_runtime.h>
#include <math.h>

#define NLAYER 4
#define BB 4
#define SS 2048
#define DD 512
#define HH 8
#define DH 64
#define FF 2048
#define TT (BB*SS)      // 8192 tokens
#define LCH 64          // attention chunk length
#define NCH (SS/LCH)    // 32 chunks
#define LN_EPS 1e-5f
#define ATT_EPS 1e-6f

typedef __bf16 bf16x8 __attribute__((ext_vector_type(8)));
typedef float  f32x4  __attribute__((ext_vector_type(4)));

__device__ __forceinline__ unsigned short f2bf(float f) {
    union { float f; unsigned u; } a; a.f = f;
    unsigned u = a.u;
    unsigned r = (u + 0x7FFFu + ((u >> 16) & 1u)) >> 16;   // RNE
    return (unsigned short)r;
}
__device__ __forceinline__ float bf2f(unsigned short s) {
    union { unsigned u; float f; } a; a.u = ((unsigned)s) << 16;
    return a.f;
}
__device__ __forceinline__ float phi_f(float u) {   // elu(u)+1
    return u > 0.f ? u + 1.f : __expf(u);
}

// ---------------- lengths ----------------
__global__ __launch_bounds__(64)
void len_kernel(const int* __restrict__ x, int* __restrict__ len) {
    const int b = blockIdx.x;
    int cnt = 0;
    for (int s = threadIdx.x; s < SS; s += 64) cnt += (x[b * SS + s] != 0);
    #pragma unroll
    for (int off = 32; off; off >>= 1) cnt += __shfl_xor(cnt, off);
    if (threadIdx.x == 0) len[b] = cnt;
}

// ---------------- embedding + positional ----------------
__global__ __launch_bounds__(256)
void embed_kernel(const int* __restrict__ x, const float* __restrict__ emb,
                  const float* __restrict__ pe, float* __restrict__ h,
                  unsigned short* __restrict__ h_bf) {
    int t = blockIdx.x * 256 + threadIdx.x;   // over TT*128 float4 slots
    int row = t >> 7;
    int q = t & 127;
    int tok = x[row];
    int s = row & (SS - 1);
    float4 e = ((const float4*)(emb + (size_t)tok * DD))[q];
    float4 p = ((const float4*)(pe + (size_t)s * DD))[q];
    float4 v; v.x = e.x + p.x; v.y = e.y + p.y; v.z = e.z + p.z; v.w = e.w + p.w;
    ((float4*)(h + (size_t)row * DD))[q] = v;
    ushort4 ub; ub.x = f2bf(v.x); ub.y = f2bf(v.y); ub.z = f2bf(v.z); ub.w = f2bf(v.w);
    ((ushort4*)(h_bf + (size_t)row * DD))[q] = ub;
}

// ---------------- transpose f32[R][C] -> bf16[C][R] ----------------
__global__ __launch_bounds__(256)
void transpose_cvt(const float* __restrict__ src, unsigned short* __restrict__ dst,
                   int R, int C, size_t srcLS, size_t dstLS) {
    __shared__ float tile[32][33];
    const int z = blockIdx.z;
    src += (size_t)z * srcLS;
    dst += (size_t)z * dstLS;
    const int c0 = blockIdx.x * 32, r0 = blockIdx.y * 32;
    const int tx = threadIdx.x & 31, ty = threadIdx.x >> 5;  // ty 0..7
    #pragma unroll
    for (int i = 0; i < 32; i += 8)
        tile[ty + i][tx] = src[(size_t)(r0 + ty + i) * C + c0 + tx];
    __syncthreads();
    #pragma unroll
    for (int i = 0; i < 32; i += 8)
        dst[(size_t)(c0 + ty + i) * R + r0 + tx] = f2bf(tile[tx][ty + i]);
}

__global__ __launch_bounds__(256)
void bias_concat(const float* __restrict__ bq, const float* __restrict__ bk,
                 const float* __restrict__ bv, float* __restrict__ bqkv) {
    int idx = blockIdx.x * 256 + threadIdx.x;
    if (idx >= NLAYER * 1536) return;
    int l = idx / 1536, n = idx % 1536;
    float v = n < 512 ? bq[l * 512 + n] : (n < 1024 ? bk[l * 512 + n - 512] : bv[l * 512 + n - 1024]);
    bqkv[idx] = v;
}

// ---------------- bf16 MFMA GEMM:  C[M,N] = A[M,K] * Bt[N,K]^T + bias ----------------
__device__ __forceinline__ void gll16(void* lds_ptr, const void* g_ptr) {
    __builtin_amdgcn_global_load_lds(
        (const __attribute__((address_space(1))) void*)g_ptr,
        (__attribute__((address_space(3))) void*)lds_ptr, 16, 0, 0);
}

template<int RELU, int WF, int WB>
__global__ __launch_bounds__(256, 2)
void gemm_bt(const unsigned short* __restrict__ A, const unsigned short* __restrict__ Bt,
             const float* __restrict__ bias, float* __restrict__ Cf,
             unsigned short* __restrict__ Cb, int M, int N, int K) {
    // 128x128 tile, BK=64, 4 waves * (4x4) 16x16x32 MFMA frags.
    // LDS layout per operand: [128 rows][8 chunks of 16B], chunk XOR-swizzled by (row&7).
    __shared__ __align__(16) char lds[2 * 2 * 128 * 64 * 2];   // 64 KiB
    const int m0 = blockIdx.x * 128;
    const int n0 = blockIdx.y * 128;
    const int tid = threadIdx.x;
    const int w = tid >> 6, lane = tid & 63;
    const int wr = w >> 1, wc = w & 1;
    const int srow = lane >> 3, scc = lane & 7;

    f32x4 acc[4][4] = {};

    auto stage = [&](int buf, int k0) {
        char* base = lds + buf * 32768;
        #pragma unroll
        for (int op = 0; op < 2; ++op) {
            const unsigned short* G = op ? Bt : A;
            const int r0 = op ? n0 : m0;
            char* obase = base + op * 16384;
            #pragma unroll
            for (int i = 0; i < 4; ++i) {
                int ii = w * 4 + i;
                int row = ii * 8 + srow;                 // row within tile
                int chunk = scc ^ (row & 7);             // pre-swizzled global source
                gll16(obase + ii * 1024,
                      G + (size_t)(r0 + row) * K + k0 + chunk * 8);
            }
        }
    };

    stage(0, 0);
    const int nt = K >> 6;
    int buf = 0;
    const int g = lane >> 4;
    const int rA = wr * 64 + (lane & 15);
    const int rB = wc * 64 + (lane & 15);

    for (int kt = 0; kt < nt; ++kt) {
        __syncthreads();   // compiler drains vmcnt(0) here -> staged tile visible
        if (kt + 1 < nt) stage(buf ^ 1, (kt + 1) << 6);
        const char* pA = lds + buf * 32768;
        const char* pB = pA + 16384;
        bf16x8 af[4][2], bfr[4][2];
        #pragma unroll
        for (int m = 0; m < 4; ++m)
            #pragma unroll
            for (int kk = 0; kk < 2; ++kk) {
                int row = rA + m * 16;
                int c = (kk * 4 + g) ^ (row & 7);
                af[m][kk] = *(const bf16x8*)(pA + row * 128 + c * 16);
            }
        #pragma unroll
        for (int n = 0; n < 4; ++n)
            #pragma unroll
            for (int kk = 0; kk < 2; ++kk) {
                int row = rB + n * 16;
                int c = (kk * 4 + g) ^ (row & 7);
                bfr[n][kk] = *(const bf16x8*)(pB + row * 128 + c * 16);
            }
        #pragma unroll
        for (int kk = 0; kk < 2; ++kk)
            #pragma unroll
            for (int m = 0; m < 4; ++m)
                #pragma unroll
                for (int n = 0; n < 4; ++n)
                    acc[m][n] = __builtin_amdgcn_mfma_f32_16x16x32_bf16(
                        af[m][kk], bfr[n][kk], acc[m][n], 0, 0, 0);
        buf ^= 1;
    }

    // epilogue: D col = lane&15, row = (lane>>4)*4 + r  (m89-verified layout)
    const int col16 = lane & 15;
    const int rgrp = lane >> 4;
    #pragma unroll
    for (int n = 0; n < 4; ++n) {
        int col = n0 + wc * 64 + n * 16 + col16;
        float bi = bias[col];
        #pragma unroll
        for (int m = 0; m < 4; ++m) {
            int rowb = m0 + wr * 64 + m * 16 + rgrp * 4;
            #pragma unroll
            for (int r = 0; r < 4; ++r) {
                float v = acc[m][n][r] + bi;
                if (RELU) v = v > 0.f ? v : 0.f;
                if (WF) Cf[(size_t)(rowb + r) * N + col] = v;
                if (WB) Cb[(size_t)(rowb + r) * N + col] = f2bf(v);
            }
        }
    }
}

// ---------------- attention pass A: per-chunk K^T V and K colsum ----------------
__global__ __launch_bounds__(256)
void attn_chunk_sums(const float* __restrict__ qkv, const int* __restrict__ len,
                     float* __restrict__ states, float* __restrict__ ksum) {
    const int c = blockIdx.x & (NCH - 1);
    const int bh = blockIdx.x / NCH;
    const int b = bh >> 3, h = bh & 7;
    const int L = len[b];
    __shared__ float Kf[LCH][DH];
    __shared__ float Vf[LCH][DH];
    const int tid = threadIdx.x;
    for (int idx = tid; idx < LCH * DH; idx += 256) {
        int jj = idx >> 6, d = idx & 63;
        int sglob = c * LCH + jj;
        const float* base = qkv + (size_t)(b * SS + sglob) * 1536 + h * 64 + d;
        float kv = base[512];
        float kp = phi_f(kv);
        Kf[jj][d] = (sglob < L) ? kp : 0.f;
        Vf[jj][d] = base[1024];
    }
    __syncthreads();
    const int d0 = (tid >> 4) * 4;     // quarter-uniform -> LDS broadcast
    const int e0 = (tid & 15) * 4;     // per-lane -> coalesced stores
    float acc[4][4] = {{0.f}};
    for (int jj = 0; jj < LCH; ++jj) {
        float4 kd = *(const float4*)&Kf[jj][d0];
        float4 ve = *(const float4*)&Vf[jj][e0];
        float kr[4] = {kd.x, kd.y, kd.z, kd.w};
        float vc[4] = {ve.x, ve.y, ve.z, ve.w};
        #pragma unroll
        for (int r = 0; r < 4; ++r)
            #pragma unroll
            for (int cc = 0; cc < 4; ++cc) acc[r][cc] += kr[r] * vc[cc];
    }
    float* so = states + (size_t)blockIdx.x * 4096;
    #pragma unroll
    for (int r = 0; r < 4; ++r) {
        float4 v; v.x = acc[r][0]; v.y = acc[r][1]; v.z = acc[r][2]; v.w = acc[r][3];
        *(float4*)&so[(d0 + r) * 64 + e0] = v;
    }
    if (tid < 64) {
        float s = 0.f;
        for (int jj = 0; jj < LCH; ++jj) s += Kf[jj][tid];
        ksum[(size_t)blockIdx.x * 64 + tid] = s;
    }
}

// ---------------- attention pass B: exclusive prefix over chunks ----------------
__global__ __launch_bounds__(256)
void attn_prefix(const float* __restrict__ states, const float* __restrict__ ksum,
                 float* __restrict__ sprefix, float* __restrict__ kprefix) {
    const int bh = blockIdx.x;
    const int tid = threadIdx.x;
    for (int idx = tid; idx < 4096; idx += 256) {
        float run = 0.f;
        for (int cc = 0; cc < NCH; ++cc) {
            size_t o = ((size_t)(bh * NCH + cc)) * 4096 + idx;
            float v = states[o];
            sprefix[o] = run;
            run += v;
        }
    }
    if (tid < 64) {
        float run = 0.f;
        for (int cc = 0; cc < NCH; ++cc) {
            size_t o = ((size_t)(bh * NCH + cc)) * 64 + tid;
            float v = ksum[o];
            kprefix[o] = run;
            run += v;
        }
    }
}

// ---------------- attention pass C: intra + inter, write bf16 ----------------
__global__ __launch_bounds__(256)
void attn_output(const float* __restrict__ qkv, const int* __restrict__ len,
                 const float* __restrict__ sprefix, const float* __restrict__ kprefix,
                 unsigned short* __restrict__ a_bf) {
    const int c = blockIdx.x & (NCH - 1);
    const int bh = blockIdx.x / NCH;
    const int b = bh >> 3, h = bh & 7;
    const int L = len[b];
    const int tid = threadIdx.x;
    __shared__ float Qf[LCH][DH + 1];       // 65-stride: conflict-free column reads
    __shared__ float Kf[LCH][DH + 1];
    __shared__ unsigned short Vb[LCH][DH];
    __shared__ float Am[LCH][DH + 1];
    __shared__ float ksp[DH];
    __shared__ float zinv[LCH];

    for (int idx = tid; idx < LCH * DH; idx += 256) {
        int jj = idx >> 6, d = idx & 63;
        int sglob = c * LCH + jj;
        const float* base = qkv + (size_t)(b * SS + sglob) * 1536 + h * 64 + d;
        float qv = base[0], kv = base[512], vv = base[1024];
        Qf[jj][d] = phi_f(qv);
        float kp = phi_f(kv);
        Kf[jj][d] = (sglob < L) ? kp : 0.f;
        Vb[jj][d] = f2bf(vv);
    }
    if (tid < 64) ksp[tid] = kprefix[(size_t)(bh * NCH + c) * 64 + tid];
    __syncthreads();

    const int r0 = (tid >> 4) * 4;     // i (quarter-uniform)
    const int c0 = (tid & 15) * 4;     // j / e (per-lane)

    // phase 1: Am[i][j] = (j<=i) ? phiQ_i . phiK_j : 0
    {
        float am[4][4] = {{0.f}};
        for (int d = 0; d < 64; ++d) {
            float qr[4], kc[4];
            #pragma unroll
            for (int r = 0; r < 4; ++r) qr[r] = Qf[r0 + r][d];
            #pragma unroll
            for (int cc = 0; cc < 4; ++cc) kc[cc] = Kf[c0 + cc][d];
            #pragma unroll
            for (int r = 0; r < 4; ++r)
                #pragma unroll
                for (int cc = 0; cc < 4; ++cc) am[r][cc] += qr[r] * kc[cc];
        }
        #pragma unroll
        for (int r = 0; r < 4; ++r)
            #pragma unroll
            for (int cc = 0; cc < 4; ++cc) {
                int i = r0 + r, j = c0 + cc;
                Am[i][j] = (j <= i) ? am[r][cc] : 0.f;
            }
    }
    __syncthreads();
    // z
    if (tid < 64) {
        int i = tid;
        float z = 0.f;
        for (int j = 0; j <= i; ++j) z += Am[i][j];
        float zq = 0.f;
        for (int d = 0; d < 64; ++d) zq += Qf[i][d] * ksp[d];
        zinv[i] = 1.f / (z + zq + ATT_EPS);
    }
    __syncthreads();
    // phase 2: out[i][e] = (Q.Sprev + Am.V) * zinv
    {
        const float* Sp = sprefix + (size_t)(bh * NCH + c) * 4096;
        float acc[4][4] = {{0.f}};
        for (int d = 0; d < 64; ++d) {
            float qr[4];
            #pragma unroll
            for (int r = 0; r < 4; ++r) qr[r] = Qf[r0 + r][d];
            float4 sp4 = *(const float4*)&Sp[d * 64 + c0];
            float sp[4] = {sp4.x, sp4.y, sp4.z, sp4.w};
            #pragma unroll
            for (int r = 0; r < 4; ++r)
                #pragma unroll
                for (int cc = 0; cc < 4; ++cc) acc[r][cc] += qr[r] * sp[cc];
        }
        for (int j = 0; j < 64; ++j) {
            float ar[4];
            #pragma unroll
            for (int r = 0; r < 4; ++r) ar[r] = Am[r0 + r][j];
            ushort4 vv = *(const ushort4*)&Vb[j][c0];
            float vc[4] = {bf2f(vv.x), bf2f(vv.y), bf2f(vv.z), bf2f(vv.w)};
            #pragma unroll
            for (int r = 0; r < 4; ++r)
                #pragma unroll
                for (int cc = 0; cc < 4; ++cc) acc[r][cc] += ar[r] * vc[cc];
        }
        #pragma unroll
        for (int r = 0; r < 4; ++r) {
            int i = r0 + r;
            float zi = zinv[i];
            int sglob = c * LCH + i;
            ushort4 ob;
            ob.x = f2bf(acc[r][0] * zi); ob.y = f2bf(acc[r][1] * zi);
            ob.z = f2bf(acc[r][2] * zi); ob.w = f2bf(acc[r][3] * zi);
            *(ushort4*)&a_bf[(size_t)(b * SS + sglob) * 512 + h * 64 + c0] = ob;
        }
    }
}

// ---------------- residual + LayerNorm (wave per row) ----------------
template<int ADD, int WB>
__global__ __launch_bounds__(64)
void ln_kernel(const float* __restrict__ hin, const float* __restrict__ add,
               const float* __restrict__ gw, const float* __restrict__ bw,
               float* __restrict__ hout, unsigned short* __restrict__ hbf) {
    const int row = blockIdx.x;
    const int lane = threadIdx.x;
    float v[8];
    const float* hp = hin + (size_t)row * DD;
    float s = 0.f;
    #pragma unroll
    for (int i = 0; i < 2; ++i) {
        int q = lane + i * 64;
        float4 a = ((const float4*)hp)[q];
        if (ADD) {
            float4 bb = ((const float4*)(add + (size_t)row * DD))[q];
            a.x += bb.x; a.y += bb.y; a.z += bb.z; a.w += bb.w;
        }
        v[i*4+0] = a.x; v[i*4+1] = a.y; v[i*4+2] = a.z; v[i*4+3] = a.w;
        s += a.x + a.y + a.z + a.w;
    }
    #pragma unroll
    for (int off = 32; off; off >>= 1) s += __shfl_xor(s, off);
    float mu = s * (1.f / 512.f);
    float sq = 0.f;
    #pragma unroll
    for (int i = 0; i < 8; ++i) { float d = v[i] - mu; sq += d * d; }
    #pragma unroll
    for (int off = 32; off; off >>= 1) sq += __shfl_xor(sq, off);
    float rs = 1.f / sqrtf(sq * (1.f / 512.f) + LN_EPS);
    #pragma unroll
    for (int i = 0; i < 2; ++i) {
        int q = lane + i * 64;
        float4 gv = ((const float4*)gw)[q];
        float4 bv = ((const float4*)bw)[q];
        float4 o;
        o.x = (v[i*4+0] - mu) * rs * gv.x + bv.x;
        o.y = (v[i*4+1] - mu) * rs * gv.y + bv.y;
        o.z = (v[i*4+2] - mu) * rs * gv.z + bv.z;
        o.w = (v[i*4+3] - mu) * rs * gv.w + bv.w;
        ((float4*)(hout + (size_t)row * DD))[q] = o;
        if (WB) {
            ushort4 ub; ub.x = f2bf(o.x); ub.y = f2bf(o.y); ub.z = f2bf(o.z); ub.w = f2bf(o.w);
            ((ushort4*)(hbf + (size_t)row * DD))[q] = ub;
        }
    }
}

// ---------------- host ----------------
extern "C" void kernel_launch(void* const* d_in, const int* in_sizes, int n_in,
                              void* d_out, int out_size, void* d_ws, size_t ws_size,
                              hipStream_t stream) {
    (void)in_sizes; (void)n_in; (void)out_size; (void)ws_size;
    const int*   x   = (const int*)d_in[0];
    const float* emb = (const float*)d_in[1];
    const float* pe  = (const float*)d_in[2];
    const float* Wq  = (const float*)d_in[3];
    const float* bq  = (const float*)d_in[4];
    const float* Wk  = (const float*)d_in[5];
    const float* bk  = (const float*)d_in[6];
    const float* Wv  = (const float*)d_in[7];
    const float* bv  = (const float*)d_in[8];
    const float* Wo  = (const float*)d_in[9];
    const float* bo  = (const float*)d_in[10];
    const float* W1  = (const float*)d_in[11];
    const float* b1  = (const float*)d_in[12];
    const float* W2  = (const float*)d_in[13];
    const float* b2  = (const float*)d_in[14];
    const float* g1  = (const float*)d_in[15];
    const float* be1 = (const float*)d_in[16];
    const float* g2  = (const float*)d_in[17];
    const float* be2 = (const float*)d_in[18];
    const float* gf  = (const float*)d_in[19];
    const float* bff = (const float*)d_in[20];
    float* out = (float*)d_out;

    char* ws = (char*)d_ws;
    size_t off = 0;
    auto alloc = [&](size_t bytes) -> void* {
        void* p = ws + off; off += (bytes + 255) & ~(size_t)255; return p;
    };
    int* len              = (int*)alloc(16);
    unsigned short* qkv_t = (unsigned short*)alloc((size_t)NLAYER * 1536 * 512 * 2);
    unsigned short* wo_t  = (unsigned short*)alloc((size_t)NLAYER * 512 * 512 * 2);
    unsigned short* w1_t  = (unsigned short*)alloc((size_t)NLAYER * 2048 * 512 * 2);
    unsigned short* w2_t  = (unsigned short*)alloc((size_t)NLAYER * 512 * 2048 * 2);
    float* bqkv           = (float*)alloc((size_t)NLAYER * 1536 * 4);
    float* h              = (float*)alloc((size_t)TT * 512 * 4);
    unsigned short* h_bf  = (unsigned short*)alloc((size_t)TT * 512 * 2);
    float* qkv            = (float*)alloc((size_t)TT * 1536 * 4);
    unsigned short* a_bf  = (unsigned short*)alloc((size_t)TT * 512 * 2);
    float* obuf           = (float*)alloc((size_t)TT * 512 * 4);
    unsigned short* y1_bf = (unsigned short*)alloc((size_t)TT * 2048 * 2);
    float* states         = (float*)alloc((size_t)32 * NCH * 4096 * 4);
    float* ksum           = (float*)alloc((size_t)32 * NCH * 64 * 4);
    float* sprefix        = (float*)alloc((size_t)32 * NCH * 4096 * 4);
    float* kprefix        = (float*)alloc((size_t)32 * NCH * 64 * 4);

    len_kernel<<<BB, 64, 0, stream>>>(x, len);
    embed_kernel<<<(TT * 128) / 256, 256, 0, stream>>>(x, emb, pe, h, h_bf);

    dim3 tb(256);
    transpose_cvt<<<dim3(16, 16, NLAYER), tb, 0, stream>>>(Wq, qkv_t,             512, 512, (size_t)512*512, (size_t)1536*512);
    transpose_cvt<<<dim3(16, 16, NLAYER), tb, 0, stream>>>(Wk, qkv_t + 512*512,   512, 512, (size_t)512*512, (size_t)1536*512);
    transpose_cvt<<<dim3(16, 16, NLAYER), tb, 0, stream>>>(Wv, qkv_t + 1024*512,  512, 512, (size_t)512*512, (size_t)1536*512);
    transpose_cvt<<<dim3(16, 16, NLAYER), tb, 0, stream>>>(Wo, wo_t,              512, 512, (size_t)512*512, (size_t)512*512);
    transpose_cvt<<<dim3(64, 16, NLAYER), tb, 0, stream>>>(W1, w1_t,              512, 2048, (size_t)512*2048, (size_t)2048*512);
    transpose_cvt<<<dim3(16, 64, NLAYER), tb, 0, stream>>>(W2, w2_t,              2048, 512, (size_t)2048*512, (size_t)512*2048);
    bias_concat<<<(NLAYER * 1536 + 255) / 256, 256, 0, stream>>>(bq, bk, bv, bqkv);

    for (int l = 0; l < NLAYER; ++l) {
        gemm_bt<0,1,0><<<dim3(TT/128, 1536/128), 256, 0, stream>>>(
            h_bf, qkv_t + (size_t)l*1536*512, bqkv + l*1536, qkv, nullptr, TT, 1536, 512);
        attn_chunk_sums<<<32 * NCH, 256, 0, stream>>>(qkv, len, states, ksum);
        attn_prefix<<<32, 256, 0, stream>>>(states, ksum, sprefix, kprefix);
        attn_output<<<32 * NCH, 256, 0, stream>>>(qkv, len, sprefix, kprefix, a_bf);
        gemm_bt<0,1,0><<<dim3(TT/128, 512/128), 256, 0, stream>>>(
            a_bf, wo_t + (size_t)l*512*512, bo + l*512, obuf, nullptr, TT, 512, 512);
        ln_kernel<1,1><<<TT, 64, 0, stream>>>(h, obuf, g1 + l*512, be1 + l*512, h, h_bf);
        gemm_bt<1,0,1><<<dim3(TT/128, 2048/128), 256, 0, stream>>>(
            h_bf, w1_t + (size_t)l*2048*512, b1 + l*2048, nullptr, y1_bf, TT, 2048, 512);
        gemm_bt<0,1,0><<<dim3(TT/128, 512/128), 256, 0, stream>>>(
            y1_bf, w2_t + (size_t)l*512*2048, b2 + l*512, obuf, nullptr, TT, 512, 2048);
        ln_kernel<1,1><<<TT, 64, 0, stream>>>(h, obuf, g2 + l*512, be2 + l*512, h, h_bf);
    }
    ln_kernel<0,0><<<TT, 64, 0, stream>>>(h, nullptr, gf, bff, out, nullptr);
}

// Round 2
// 739.809 us; speedup vs baseline: 1.2795x; 1.2795x over previous
//
#include <hip/hip_runtime.h>
#include <math.h>

#define NLAYER 4
#define BB 4
#define SS 2048
#define DD 512
#define HH 8
#define DH 64
#define FF 2048
#define TT (BB*SS)      // 8192 tokens
#define LCH 64          // attention chunk length
#define NCH (SS/LCH)    // 32 chunks
#define LN_EPS 1e-5f
#define ATT_EPS 1e-6f

typedef __bf16 bf16x8 __attribute__((ext_vector_type(8)));
typedef float  f32x4  __attribute__((ext_vector_type(4)));

__device__ __forceinline__ unsigned short f2bf(float f) {
    union { float f; unsigned u; } a; a.f = f;
    unsigned u = a.u;
    unsigned r = (u + 0x7FFFu + ((u >> 16) & 1u)) >> 16;   // RNE
    return (unsigned short)r;
}
__device__ __forceinline__ float bf2f(unsigned short s) {
    union { unsigned u; float f; } a; a.u = ((unsigned)s) << 16;
    return a.f;
}
__device__ __forceinline__ float phi_f(float u) {   // elu(u)+1
    return u > 0.f ? u + 1.f : __expf(u);
}

// ---------------- lengths ----------------
__global__ __launch_bounds__(64)
void len_kernel(const int* __restrict__ x, int* __restrict__ len) {
    const int b = blockIdx.x;
    int cnt = 0;
    for (int s = threadIdx.x; s < SS; s += 64) cnt += (x[b * SS + s] != 0);
    #pragma unroll
    for (int off = 32; off; off >>= 1) cnt += __shfl_xor(cnt, off);
    if (threadIdx.x == 0) len[b] = cnt;
}

// ---------------- embedding + positional ----------------
__global__ __launch_bounds__(256)
void embed_kernel(const int* __restrict__ x, const float* __restrict__ emb,
                  const float* __restrict__ pe, float* __restrict__ h,
                  unsigned short* __restrict__ h_bf) {
    int t = blockIdx.x * 256 + threadIdx.x;   // over TT*128 float4 slots
    int row = t >> 7;
    int q = t & 127;
    int tok = x[row];
    int s = row & (SS - 1);
    float4 e = ((const float4*)(emb + (size_t)tok * DD))[q];
    float4 p = ((const float4*)(pe + (size_t)s * DD))[q];
    float4 v; v.x = e.x + p.x; v.y = e.y + p.y; v.z = e.z + p.z; v.w = e.w + p.w;
    ((float4*)(h + (size_t)row * DD))[q] = v;
    ushort4 ub; ub.x = f2bf(v.x); ub.y = f2bf(v.y); ub.z = f2bf(v.z); ub.w = f2bf(v.w);
    ((ushort4*)(h_bf + (size_t)row * DD))[q] = ub;
}

// ---------------- transpose f32[R][C] -> bf16[C][R] ----------------
__global__ __launch_bounds__(256)
void transpose_cvt(const float* __restrict__ src, unsigned short* __restrict__ dst,
                   int R, int C, size_t srcLS, size_t dstLS) {
    __shared__ float tile[32][33];
    const int z = blockIdx.z;
    src += (size_t)z * srcLS;
    dst += (size_t)z * dstLS;
    const int c0 = blockIdx.x * 32, r0 = blockIdx.y * 32;
    const int tx = threadIdx.x & 31, ty = threadIdx.x >> 5;  // ty 0..7
    #pragma unroll
    for (int i = 0; i < 32; i += 8)
        tile[ty + i][tx] = src[(size_t)(r0 + ty + i) * C + c0 + tx];
    __syncthreads();
    #pragma unroll
    for (int i = 0; i < 32; i += 8)
        dst[(size_t)(c0 + ty + i) * R + r0 + tx] = f2bf(tile[tx][ty + i]);
}

__global__ __launch_bounds__(256)
void bias_concat(const float* __restrict__ bq, const float* __restrict__ bk,
                 const float* __restrict__ bv, float* __restrict__ bqkv) {
    int idx = blockIdx.x * 256 + threadIdx.x;
    if (idx >= NLAYER * 1536) return;
    int l = idx / 1536, n = idx % 1536;
    float v = n < 512 ? bq[l * 512 + n] : (n < 1024 ? bk[l * 512 + n - 512] : bv[l * 512 + n - 1024]);
    bqkv[idx] = v;
}

// ---------------- bf16 MFMA GEMM:  C[M,N] = A[M,K] * Bt[N,K]^T + bias ----------------
__device__ __forceinline__ void gll16(void* lds_ptr, const void* g_ptr) {
    __builtin_amdgcn_global_load_lds(
        (const __attribute__((address_space(1))) void*)g_ptr,
        (__attribute__((address_space(3))) void*)lds_ptr, 16, 0, 0);
}

template<int RELU, int WF, int WB>
__global__ __launch_bounds__(256, 2)
void gemm_bt(const unsigned short* __restrict__ A, const unsigned short* __restrict__ Bt,
             const float* __restrict__ bias, float* __restrict__ Cf,
             unsigned short* __restrict__ Cb, int M, int N, int K) {
    // 128x128 tile, BK=64, 4 waves * (4x4) 16x16x32 MFMA frags.
    // LDS layout per operand: [128 rows][8 chunks of 16B], chunk XOR-swizzled by (row&7).
    __shared__ __align__(16) char lds[2 * 2 * 128 * 64 * 2];   // 64 KiB
    const int m0 = blockIdx.x * 128;
    const int n0 = blockIdx.y * 128;
    const int tid = threadIdx.x;
    const int w = tid >> 6, lane = tid & 63;
    const int wr = w >> 1, wc = w & 1;
    const int srow = lane >> 3, scc = lane & 7;

    f32x4 acc[4][4] = {};

    auto stage = [&](int buf, int k0) {
        char* base = lds + buf * 32768;
        #pragma unroll
        for (int op = 0; op < 2; ++op) {
            const unsigned short* G = op ? Bt : A;
            const int r0 = op ? n0 : m0;
            char* obase = base + op * 16384;
            #pragma unroll
            for (int i = 0; i < 4; ++i) {
                int ii = w * 4 + i;
                int row = ii * 8 + srow;                 // row within tile
                int chunk = scc ^ (row & 7);             // pre-swizzled global source
                gll16(obase + ii * 1024,
                      G + (size_t)(r0 + row) * K + k0 + chunk * 8);
            }
        }
    };

    stage(0, 0);
    const int nt = K >> 6;
    int buf = 0;
    const int g = lane >> 4;
    const int rA = wr * 64 + (lane & 15);
    const int rB = wc * 64 + (lane & 15);

    for (int kt = 0; kt < nt; ++kt) {
        __syncthreads();   // compiler drains vmcnt(0) here -> staged tile visible
        if (kt + 1 < nt) stage(buf ^ 1, (kt + 1) << 6);
        const char* pA = lds + buf * 32768;
        const char* pB = pA + 16384;
        bf16x8 af[4][2], bfr[4][2];
        #pragma unroll
        for (int m = 0; m < 4; ++m)
            #pragma unroll
            for (int kk = 0; kk < 2; ++kk) {
                int row = rA + m * 16;
                int c = (kk * 4 + g) ^ (row & 7);
                af[m][kk] = *(const bf16x8*)(pA + row * 128 + c * 16);
            }
        #pragma unroll
        for (int n = 0; n < 4; ++n)
            #pragma unroll
            for (int kk = 0; kk < 2; ++kk) {
                int row = rB + n * 16;
                int c = (kk * 4 + g) ^ (row & 7);
                bfr[n][kk] = *(const bf16x8*)(pB + row * 128 + c * 16);
            }
        #pragma unroll
        for (int kk = 0; kk < 2; ++kk)
            #pragma unroll
            for (int m = 0; m < 4; ++m)
                #pragma unroll
                for (int n = 0; n < 4; ++n)
                    acc[m][n] = __builtin_amdgcn_mfma_f32_16x16x32_bf16(
                        af[m][kk], bfr[n][kk], acc[m][n], 0, 0, 0);
        buf ^= 1;
    }

    // epilogue: D col = lane&15, row = (lane>>4)*4 + r  (m89-verified layout)
    const int col16 = lane & 15;
    const int rgrp = lane >> 4;
    #pragma unroll
    for (int n = 0; n < 4; ++n) {
        int col = n0 + wc * 64 + n * 16 + col16;
        float bi = bias[col];
        #pragma unroll
        for (int m = 0; m < 4; ++m) {
            int rowb = m0 + wr * 64 + m * 16 + rgrp * 4;
            #pragma unroll
            for (int r = 0; r < 4; ++r) {
                float v = acc[m][n][r] + bi;
                if (RELU) v = v > 0.f ? v : 0.f;
                if (WF) Cf[(size_t)(rowb + r) * N + col] = v;
                if (WB) Cb[(size_t)(rowb + r) * N + col] = f2bf(v);
            }
        }
    }
}

// ---------------- attention pass A: per-chunk K^T V and K colsum ----------------
__global__ __launch_bounds__(256)
void attn_chunk_sums(const float* __restrict__ qkv, const int* __restrict__ len,
                     float* __restrict__ states, float* __restrict__ ksum) {
    const int c = blockIdx.x & (NCH - 1);
    const int bh = blockIdx.x / NCH;
    const int b = bh >> 3, h = bh & 7;
    const int L = len[b];
    __shared__ float Kf[LCH][DH];
    __shared__ float Vf[LCH][DH];
    const int tid = threadIdx.x;
    for (int idx = tid; idx < LCH * DH; idx += 256) {
        int jj = idx >> 6, d = idx & 63;
        int sglob = c * LCH + jj;
        const float* base = qkv + (size_t)(b * SS + sglob) * 1536 + h * 64 + d;
        float kv = base[512];
        float kp = phi_f(kv);
        Kf[jj][d] = (sglob < L) ? kp : 0.f;
        Vf[jj][d] = base[1024];
    }
    __syncthreads();
    const int d0 = (tid >> 4) * 4;     // quarter-uniform -> LDS broadcast
    const int e0 = (tid & 15) * 4;     // per-lane -> coalesced stores
    float acc[4][4] = {{0.f}};
    for (int jj = 0; jj < LCH; ++jj) {
        float4 kd = *(const float4*)&Kf[jj][d0];
        float4 ve = *(const float4*)&Vf[jj][e0];
        float kr[4] = {kd.x, kd.y, kd.z, kd.w};
        float vc[4] = {ve.x, ve.y, ve.z, ve.w};
        #pragma unroll
        for (int r = 0; r < 4; ++r)
            #pragma unroll
            for (int cc = 0; cc < 4; ++cc) acc[r][cc] += kr[r] * vc[cc];
    }
    float* so = states + (size_t)blockIdx.x * 4096;
    #pragma unroll
    for (int r = 0; r < 4; ++r) {
        float4 v; v.x = acc[r][0]; v.y = acc[r][1]; v.z = acc[r][2]; v.w = acc[r][3];
        *(float4*)&so[(d0 + r) * 64 + e0] = v;
    }
    if (tid < 64) {
        float s = 0.f;
        for (int jj = 0; jj < LCH; ++jj) s += Kf[jj][tid];
        ksum[(size_t)blockIdx.x * 64 + tid] = s;
    }
}

// ---------------- attention pass B: exclusive prefix over chunks ----------------
// grid: 32 bh * 16 idx-blocks, 256 threads; one thread per (bh, idx).
__global__ __launch_bounds__(256)
void attn_prefix(const float* __restrict__ states, const float* __restrict__ ksum,
                 float* __restrict__ sprefix, float* __restrict__ kprefix) {
    const int bh = blockIdx.x >> 4;
    const int idx = (blockIdx.x & 15) * 256 + threadIdx.x;
    size_t base = (size_t)bh * NCH * 4096 + idx;
    float run = 0.f;
    #pragma unroll 4
    for (int cc = 0; cc < NCH; ++cc) {
        size_t o = base + (size_t)cc * 4096;
        float v = states[o];
        sprefix[o] = run;
        run += v;
    }
    if ((blockIdx.x & 15) == 0 && threadIdx.x < 64) {
        size_t kb = (size_t)bh * NCH * 64 + threadIdx.x;
        float krun = 0.f;
        for (int cc = 0; cc < NCH; ++cc) {
            size_t o = kb + (size_t)cc * 64;
            float v = ksum[o];
            kprefix[o] = krun;
            krun += v;
        }
    }
}

// ---------------- attention pass C: intra + inter, write bf16 ----------------
__global__ __launch_bounds__(256)
void attn_output(const float* __restrict__ qkv, const int* __restrict__ len,
                 const float* __restrict__ sprefix, const float* __restrict__ kprefix,
                 unsigned short* __restrict__ a_bf) {
    const int c = blockIdx.x & (NCH - 1);
    const int bh = blockIdx.x / NCH;
    const int b = bh >> 3, h = bh & 7;
    const int L = len[b];
    const int tid = threadIdx.x;
    __shared__ float Qf[LCH][DH + 1];       // 65-stride: conflict-free column reads
    __shared__ float Kf[LCH][DH + 1];
    __shared__ unsigned short Vb[LCH][DH];
    __shared__ float Am[LCH][DH + 1];
    __shared__ float ksp[DH];
    __shared__ float zinv[LCH];

    for (int idx = tid; idx < LCH * DH; idx += 256) {
        int jj = idx >> 6, d = idx & 63;
        int sglob = c * LCH + jj;
        const float* base = qkv + (size_t)(b * SS + sglob) * 1536 + h * 64 + d;
        float qv = base[0], kv = base[512], vv = base[1024];
        Qf[jj][d] = phi_f(qv);
        float kp = phi_f(kv);
        Kf[jj][d] = (sglob < L) ? kp : 0.f;
        Vb[jj][d] = f2bf(vv);
    }
    if (tid < 64) ksp[tid] = kprefix[(size_t)(bh * NCH + c) * 64 + tid];
    __syncthreads();

    const int r0 = (tid >> 4) * 4;     // i (quarter-uniform)
    const int c0 = (tid & 15) * 4;     // j / e (per-lane)

    // phase 1: Am[i][j] = (j<=i) ? phiQ_i . phiK_j : 0
    {
        float am[4][4] = {{0.f}};
        for (int d = 0; d < 64; ++d) {
            float qr[4], kc[4];
            #pragma unroll
            for (int r = 0; r < 4; ++r) qr[r] = Qf[r0 + r][d];
            #pragma unroll
            for (int cc = 0; cc < 4; ++cc) kc[cc] = Kf[c0 + cc][d];
            #pragma unroll
            for (int r = 0; r < 4; ++r)
                #pragma unroll
                for (int cc = 0; cc < 4; ++cc) am[r][cc] += qr[r] * kc[cc];
        }
        #pragma unroll
        for (int r = 0; r < 4; ++r)
            #pragma unroll
            for (int cc = 0; cc < 4; ++cc) {
                int i = r0 + r, j = c0 + cc;
                Am[i][j] = (j <= i) ? am[r][cc] : 0.f;
            }
    }
    __syncthreads();
    // z
    if (tid < 64) {
        int i = tid;
        float z = 0.f;
        for (int j = 0; j <= i; ++j) z += Am[i][j];
        float zq = 0.f;
        for (int d = 0; d < 64; ++d) zq += Qf[i][d] * ksp[d];
        zinv[i] = 1.f / (z + zq + ATT_EPS);
    }
    __syncthreads();
    // phase 2: out[i][e] = (Q.Sprev + Am.V) * zinv
    {
        const float* Sp = sprefix + (size_t)(bh * NCH + c) * 4096;
        float acc[4][4] = {{0.f}};
        for (int d = 0; d < 64; ++d) {
            float qr[4];
            #pragma unroll
            for (int r = 0; r < 4; ++r) qr[r] = Qf[r0 + r][d];
            float4 sp4 = *(const float4*)&Sp[d * 64 + c0];
            float sp[4] = {sp4.x, sp4.y, sp4.z, sp4.w};
            #pragma unroll
            for (int r = 0; r < 4; ++r)
                #pragma unroll
                for (int cc = 0; cc < 4; ++cc) acc[r][cc] += qr[r] * sp[cc];
        }
        for (int j = 0; j < 64; ++j) {
            float ar[4];
            #pragma unroll
            for (int r = 0; r < 4; ++r) ar[r] = Am[r0 + r][j];
            ushort4 vv = *(const ushort4*)&Vb[j][c0];
            float vc[4] = {bf2f(vv.x), bf2f(vv.y), bf2f(vv.z), bf2f(vv.w)};
            #pragma unroll
            for (int r = 0; r < 4; ++r)
                #pragma unroll
                for (int cc = 0; cc < 4; ++cc) acc[r][cc] += ar[r] * vc[cc];
        }
        #pragma unroll
        for (int r = 0; r < 4; ++r) {
            int i = r0 + r;
            float zi = zinv[i];
            int sglob = c * LCH + i;
            ushort4 ob;
            ob.x = f2bf(acc[r][0] * zi); ob.y = f2bf(acc[r][1] * zi);
            ob.z = f2bf(acc[r][2] * zi); ob.w = f2bf(acc[r][3] * zi);
            *(ushort4*)&a_bf[(size_t)(b * SS + sglob) * 512 + h * 64 + c0] = ob;
        }
    }
}

// ---------------- residual + LayerNorm (wave per row) ----------------
template<int ADD, int WB>
__global__ __launch_bounds__(64)
void ln_kernel(const float* __restrict__ hin, const float* __restrict__ add,
               const float* __restrict__ gw, const float* __restrict__ bw,
               float* __restrict__ hout, unsigned short* __restrict__ hbf) {
    const int row = blockIdx.x;
    const int lane = threadIdx.x;
    float v[8];
    const float* hp = hin + (size_t)row * DD;
    float s = 0.f;
    #pragma unroll
    for (int i = 0; i < 2; ++i) {
        int q = lane + i * 64;
        float4 a = ((const float4*)hp)[q];
        if (ADD) {
            float4 bb = ((const float4*)(add + (size_t)row * DD))[q];
            a.x += bb.x; a.y += bb.y; a.z += bb.z; a.w += bb.w;
        }
        v[i*4+0] = a.x; v[i*4+1] = a.y; v[i*4+2] = a.z; v[i*4+3] = a.w;
        s += a.x + a.y + a.z + a.w;
    }
    #pragma unroll
    for (int off = 32; off; off >>= 1) s += __shfl_xor(s, off);
    float mu = s * (1.f / 512.f);
    float sq = 0.f;
    #pragma unroll
    for (int i = 0; i < 8; ++i) { float d = v[i] - mu; sq += d * d; }
    #pragma unroll
    for (int off = 32; off; off >>= 1) sq += __shfl_xor(sq, off);
    float rs = 1.f / sqrtf(sq * (1.f / 512.f) + LN_EPS);
    #pragma unroll
    for (int i = 0; i < 2; ++i) {
        int q = lane + i * 64;
        float4 gv = ((const float4*)gw)[q];
        float4 bv = ((const float4*)bw)[q];
        float4 o;
        o.x = (v[i*4+0] - mu) * rs * gv.x + bv.x;
        o.y = (v[i*4+1] - mu) * rs * gv.y + bv.y;
        o.z = (v[i*4+2] - mu) * rs * gv.z + bv.z;
        o.w = (v[i*4+3] - mu) * rs * gv.w + bv.w;
        ((float4*)(hout + (size_t)row * DD))[q] = o;
        if (WB) {
            ushort4 ub; ub.x = f2bf(o.x); ub.y = f2bf(o.y); ub.z = f2bf(o.z); ub.w = f2bf(o.w);
            ((ushort4*)(hbf + (size_t)row * DD))[q] = ub;
        }
    }
}

// ---------------- host ----------------
extern "C" void kernel_launch(void* const* d_in, const int* in_sizes, int n_in,
                              void* d_out, int out_size, void* d_ws, size_t ws_size,
                              hipStream_t stream) {
    (void)in_sizes; (void)n_in; (void)out_size; (void)ws_size;
    const int*   x   = (const int*)d_in[0];
    const float* emb = (const float*)d_in[1];
    const float* pe  = (const float*)d_in[2];
    const float* Wq  = (const float*)d_in[3];
    const float* bq  = (const float*)d_in[4];
    const float* Wk  = (const float*)d_in[5];
    const float* bk  = (const float*)d_in[6];
    const float* Wv  = (const float*)d_in[7];
    const float* bv  = (const float*)d_in[8];
    const float* Wo  = (const float*)d_in[9];
    const float* bo  = (const float*)d_in[10];
    const float* W1  = (const float*)d_in[11];
    const float* b1  = (const float*)d_in[12];
    const float* W2  = (const float*)d_in[13];
    const float* b2  = (const float*)d_in[14];
    const float* g1  = (const float*)d_in[15];
    const float* be1 = (const float*)d_in[16];
    const float* g2  = (const float*)d_in[17];
    const float* be2 = (const float*)d_in[18];
    const float* gf  = (const float*)d_in[19];
    const float* bff = (const float*)d_in[20];
    float* out = (float*)d_out;

    char* ws = (char*)d_ws;
    size_t off = 0;
    auto alloc = [&](size_t bytes) -> void* {
        void* p = ws + off; off += (bytes + 255) & ~(size_t)255; return p;
    };
    int* len              = (int*)alloc(16);
    unsigned short* qkv_t = (unsigned short*)alloc((size_t)NLAYER * 1536 * 512 * 2);
    unsigned short* wo_t  = (unsigned short*)alloc((size_t)NLAYER * 512 * 512 * 2);
    unsigned short* w1_t  = (unsigned short*)alloc((size_t)NLAYER * 2048 * 512 * 2);
    unsigned short* w2_t  = (unsigned short*)alloc((size_t)NLAYER * 512 * 2048 * 2);
    float* bqkv           = (float*)alloc((size_t)NLAYER * 1536 * 4);
    float* h              = (float*)alloc((size_t)TT * 512 * 4);
    unsigned short* h_bf  = (unsigned short*)alloc((size_t)TT * 512 * 2);
    float* qkv            = (float*)alloc((size_t)TT * 1536 * 4);
    unsigned short* a_bf  = (unsigned short*)alloc((size_t)TT * 512 * 2);
    float* obuf           = (float*)alloc((size_t)TT * 512 * 4);
    unsigned short* y1_bf = (unsigned short*)alloc((size_t)TT * 2048 * 2);
    float* states         = (float*)alloc((size_t)32 * NCH * 4096 * 4);
    float* ksum           = (float*)alloc((size_t)32 * NCH * 64 * 4);
    float* sprefix        = (float*)alloc((size_t)32 * NCH * 4096 * 4);
    float* kprefix        = (float*)alloc((size_t)32 * NCH * 64 * 4);

    len_kernel<<<BB, 64, 0, stream>>>(x, len);
    embed_kernel<<<(TT * 128) / 256, 256, 0, stream>>>(x, emb, pe, h, h_bf);

    dim3 tb(256);
    transpose_cvt<<<dim3(16, 16, NLAYER), tb, 0, stream>>>(Wq, qkv_t,             512, 512, (size_t)512*512, (size_t)1536*512);
    transpose_cvt<<<dim3(16, 16, NLAYER), tb, 0, stream>>>(Wk, qkv_t + 512*512,   512, 512, (size_t)512*512, (size_t)1536*512);
    transpose_cvt<<<dim3(16, 16, NLAYER), tb, 0, stream>>>(Wv, qkv_t + 1024*512,  512, 512, (size_t)512*512, (size_t)1536*512);
    transpose_cvt<<<dim3(16, 16, NLAYER), tb, 0, stream>>>(Wo, wo_t,              512, 512, (size_t)512*512, (size_t)512*512);
    transpose_cvt<<<dim3(64, 16, NLAYER), tb, 0, stream>>>(W1, w1_t,              512, 2048, (size_t)512*2048, (size_t)2048*512);
    transpose_cvt<<<dim3(16, 64, NLAYER), tb, 0, stream>>>(W2, w2_t,              2048, 512, (size_t)2048*512, (size_t)512*2048);
    bias_concat<<<(NLAYER * 1536 + 255) / 256, 256, 0, stream>>>(bq, bk, bv, bqkv);

    for (int l = 0; l < NLAYER; ++l) {
        gemm_bt<0,1,0><<<dim3(TT/128, 1536/128), 256, 0, stream>>>(
            h_bf, qkv_t + (size_t)l*1536*512, bqkv + l*1536, qkv, nullptr, TT, 1536, 512);
        attn_chunk_sums<<<32 * NCH, 256, 0, stream>>>(qkv, len, states, ksum);
        attn_prefix<<<32 * 16, 256, 0, stream>>>(states, ksum, sprefix, kprefix);
        attn_output<<<32 * NCH, 256, 0, stream>>>(qkv, len, sprefix, kprefix, a_bf);
        gemm_bt<0,1,0><<<dim3(TT/128, 512/128), 256, 0, stream>>>(
            a_bf, wo_t + (size_t)l*512*512, bo + l*512, obuf, nullptr, TT, 512, 512);
        ln_kernel<1,1><<<TT, 64, 0, stream>>>(h, obuf, g1 + l*512, be1 + l*512, h, h_bf);
        gemm_bt<1,0,1><<<dim3(TT/128, 2048/128), 256, 0, stream>>>(
            h_bf, w1_t + (size_t)l*2048*512, b1 + l*2048, nullptr, y1_bf, TT, 2048, 512);
        gemm_bt<0,1,0><<<dim3(TT/128, 512/128), 256, 0, stream>>>(
            y1_bf, w2_t + (size_t)l*512*2048, b2 + l*512, obuf, nullptr, TT, 512, 2048);
        ln_kernel<1,1><<<TT, 64, 0, stream>>>(h, obuf, g2 + l*512, be2 + l*512, h, h_bf);
    }
    ln_kernel<0,0><<<TT, 64, 0, stream>>>(h, nullptr, gf, bff, out, nullptr);
}

// Round 3
// 648.871 us; speedup vs baseline: 1.4588x; 1.1401x over previous
//
#include <hip/hip_runtime.h>
#include <math.h>

#define NLAYER 4
#define BB 4
#define SS 2048
#define DD 512
#define HH 8
#define DH 64
#define FF 2048
#define TT (BB*SS)      // 8192 tokens
#define LCH 64          // attention chunk length
#define NCH (SS/LCH)    // 32 chunks
#define LN_EPS 1e-5f
#define ATT_EPS 1e-6f

typedef __bf16 bf16x8 __attribute__((ext_vector_type(8)));
typedef float  f32x4  __attribute__((ext_vector_type(4)));

__device__ __forceinline__ unsigned short f2bf(float f) {
    union { float f; unsigned u; } a; a.f = f;
    unsigned u = a.u;
    unsigned r = (u + 0x7FFFu + ((u >> 16) & 1u)) >> 16;   // RNE
    return (unsigned short)r;
}
__device__ __forceinline__ float bf2f(unsigned short s) {
    union { unsigned u; float f; } a; a.u = ((unsigned)s) << 16;
    return a.f;
}
__device__ __forceinline__ float phi_f(float u) {   // elu(u)+1
    return u > 0.f ? u + 1.f : __expf(u);
}

// ---------------- lengths ----------------
__global__ __launch_bounds__(64)
void len_kernel(const int* __restrict__ x, int* __restrict__ len) {
    const int b = blockIdx.x;
    int cnt = 0;
    for (int s = threadIdx.x; s < SS; s += 64) cnt += (x[b * SS + s] != 0);
    #pragma unroll
    for (int off = 32; off; off >>= 1) cnt += __shfl_xor(cnt, off);
    if (threadIdx.x == 0) len[b] = cnt;
}

// ---------------- embedding + positional ----------------
__global__ __launch_bounds__(256)
void embed_kernel(const int* __restrict__ x, const float* __restrict__ emb,
                  const float* __restrict__ pe, float* __restrict__ h,
                  unsigned short* __restrict__ h_bf) {
    int t = blockIdx.x * 256 + threadIdx.x;   // over TT*128 float4 slots
    int row = t >> 7;
    int q = t & 127;
    int tok = x[row];
    int s = row & (SS - 1);
    float4 e = ((const float4*)(emb + (size_t)tok * DD))[q];
    float4 p = ((const float4*)(pe + (size_t)s * DD))[q];
    float4 v; v.x = e.x + p.x; v.y = e.y + p.y; v.z = e.z + p.z; v.w = e.w + p.w;
    ((float4*)(h + (size_t)row * DD))[q] = v;
    ushort4 ub; ub.x = f2bf(v.x); ub.y = f2bf(v.y); ub.z = f2bf(v.z); ub.w = f2bf(v.w);
    ((ushort4*)(h_bf + (size_t)row * DD))[q] = ub;
}

// ---------------- transpose f32[R][C] -> bf16[C][R] ----------------
__global__ __launch_bounds__(256)
void transpose_cvt(const float* __restrict__ src, unsigned short* __restrict__ dst,
                   int R, int C, size_t srcLS, size_t dstLS) {
    __shared__ float tile[32][33];
    const int z = blockIdx.z;
    src += (size_t)z * srcLS;
    dst += (size_t)z * dstLS;
    const int c0 = blockIdx.x * 32, r0 = blockIdx.y * 32;
    const int tx = threadIdx.x & 31, ty = threadIdx.x >> 5;  // ty 0..7
    #pragma unroll
    for (int i = 0; i < 32; i += 8)
        tile[ty + i][tx] = src[(size_t)(r0 + ty + i) * C + c0 + tx];
    __syncthreads();
    #pragma unroll
    for (int i = 0; i < 32; i += 8)
        dst[(size_t)(c0 + ty + i) * R + r0 + tx] = f2bf(tile[tx][ty + i]);
}

__global__ __launch_bounds__(256)
void bias_concat(const float* __restrict__ bq, const float* __restrict__ bk,
                 const float* __restrict__ bv, float* __restrict__ bqkv) {
    int idx = blockIdx.x * 256 + threadIdx.x;
    if (idx >= NLAYER * 1536) return;
    int l = idx / 1536, n = idx % 1536;
    float v = n < 512 ? bq[l * 512 + n] : (n < 1024 ? bk[l * 512 + n - 512] : bv[l * 512 + n - 1024]);
    bqkv[idx] = v;
}

// ---------------- bf16 MFMA GEMM:  C[M,N] = A[M,K] * Bt[N,K]^T + bias ----------------
__device__ __forceinline__ void gll16(void* lds_ptr, const void* g_ptr) {
    __builtin_amdgcn_global_load_lds(
        (const __attribute__((address_space(1))) void*)g_ptr,
        (__attribute__((address_space(3))) void*)lds_ptr, 16, 0, 0);
}

template<int RELU, int WF, int WB>
__global__ __launch_bounds__(256, 2)
void gemm_bt(const unsigned short* __restrict__ A, const unsigned short* __restrict__ Bt,
             const float* __restrict__ bias, float* __restrict__ Cf,
             unsigned short* __restrict__ Cb, int M, int N, int K) {
    // 128x128 tile, BK=64, 4 waves * (4x4) 16x16x32 MFMA frags.
    __shared__ __align__(16) char lds[2 * 2 * 128 * 64 * 2];   // 64 KiB
    const int m0 = blockIdx.x * 128;
    const int n0 = blockIdx.y * 128;
    const int tid = threadIdx.x;
    const int w = tid >> 6, lane = tid & 63;
    const int wr = w >> 1, wc = w & 1;
    const int srow = lane >> 3, scc = lane & 7;

    f32x4 acc[4][4] = {};

    auto stage = [&](int buf, int k0) {
        char* base = lds + buf * 32768;
        #pragma unroll
        for (int op = 0; op < 2; ++op) {
            const unsigned short* G = op ? Bt : A;
            const int r0 = op ? n0 : m0;
            char* obase = base + op * 16384;
            #pragma unroll
            for (int i = 0; i < 4; ++i) {
                int ii = w * 4 + i;
                int row = ii * 8 + srow;                 // row within tile
                int chunk = scc ^ (row & 7);             // pre-swizzled global source
                gll16(obase + ii * 1024,
                      G + (size_t)(r0 + row) * K + k0 + chunk * 8);
            }
        }
    };

    stage(0, 0);
    const int nt = K >> 6;
    int buf = 0;
    const int g = lane >> 4;
    const int rA = wr * 64 + (lane & 15);
    const int rB = wc * 64 + (lane & 15);

    for (int kt = 0; kt < nt; ++kt) {
        __syncthreads();
        if (kt + 1 < nt) stage(buf ^ 1, (kt + 1) << 6);
        const char* pA = lds + buf * 32768;
        const char* pB = pA + 16384;
        bf16x8 af[4][2], bfr[4][2];
        #pragma unroll
        for (int m = 0; m < 4; ++m)
            #pragma unroll
            for (int kk = 0; kk < 2; ++kk) {
                int row = rA + m * 16;
                int c = (kk * 4 + g) ^ (row & 7);
                af[m][kk] = *(const bf16x8*)(pA + row * 128 + c * 16);
            }
        #pragma unroll
        for (int n = 0; n < 4; ++n)
            #pragma unroll
            for (int kk = 0; kk < 2; ++kk) {
                int row = rB + n * 16;
                int c = (kk * 4 + g) ^ (row & 7);
                bfr[n][kk] = *(const bf16x8*)(pB + row * 128 + c * 16);
            }
        #pragma unroll
        for (int kk = 0; kk < 2; ++kk)
            #pragma unroll
            for (int m = 0; m < 4; ++m)
                #pragma unroll
                for (int n = 0; n < 4; ++n)
                    acc[m][n] = __builtin_amdgcn_mfma_f32_16x16x32_bf16(
                        af[m][kk], bfr[n][kk], acc[m][n], 0, 0, 0);
        buf ^= 1;
    }

    const int col16 = lane & 15;
    const int rgrp = lane >> 4;
    #pragma unroll
    for (int n = 0; n < 4; ++n) {
        int col = n0 + wc * 64 + n * 16 + col16;
        float bi = bias[col];
        #pragma unroll
        for (int m = 0; m < 4; ++m) {
            int rowb = m0 + wr * 64 + m * 16 + rgrp * 4;
            #pragma unroll
            for (int r = 0; r < 4; ++r) {
                float v = acc[m][n][r] + bi;
                if (RELU) v = v > 0.f ? v : 0.f;
                if (WF) Cf[(size_t)(rowb + r) * N + col] = v;
                if (WB) Cb[(size_t)(rowb + r) * N + col] = f2bf(v);
            }
        }
    }
}

// ---------------- attention pass A (MFMA): states = K^T V, ksum ----------------
__global__ __launch_bounds__(256)
void attn_chunk_sums(const float* __restrict__ qkv, const int* __restrict__ len,
                     float* __restrict__ states, float* __restrict__ ksum) {
    const int c = blockIdx.x & (NCH - 1);
    const int bh = blockIdx.x / NCH;
    const int b = bh >> 3, h = bh & 7;
    const int L = len[b];
    const int tid = threadIdx.x;
    const int w = tid >> 6, lane = tid & 63;
    __shared__ __align__(16) unsigned short Kt[64 * 64];   // [d][j], swizzled
    __shared__ __align__(16) unsigned short Vt[64 * 64];   // [e][j], swizzled
    __shared__ float ksumP[4][64];

    float kpart = 0.f;
    #pragma unroll 8
    for (int t = 0; t < 16; ++t) {
        const int jj = 4 * t + w;
        const int d = lane;
        const int sglob = c * 64 + jj;
        const float* base = qkv + (size_t)(b * SS + sglob) * 1536 + h * 64 + d;
        float kv = base[512], vv = base[1024];
        float kp = (sglob < L) ? phi_f(kv) : 0.f;
        kpart += kp;
        const int sw = (((jj >> 3) ^ (d & 7)) << 3) + (jj & 7);
        Kt[d * 64 + sw] = f2bf(kp);
        Vt[d * 64 + sw] = f2bf(vv);
    }
    ksumP[w][lane] = kpart;
    __syncthreads();

    const int frow = w * 16 + (lane & 15);   // d-row of output
    const int g = lane >> 4;
    bf16x8 ak[2];
    #pragma unroll
    for (int kk = 0; kk < 2; ++kk)
        ak[kk] = *(const bf16x8*)&Kt[frow * 64 + (((kk * 4 + g) ^ (frow & 7)) << 3)];
    f32x4 oc[4] = {};
    #pragma unroll
    for (int ef = 0; ef < 4; ++ef) {
        int brow = ef * 16 + (lane & 15);
        #pragma unroll
        for (int kk = 0; kk < 2; ++kk) {
            bf16x8 bv = *(const bf16x8*)&Vt[brow * 64 + (((kk * 4 + g) ^ (brow & 7)) << 3)];
            oc[ef] = __builtin_amdgcn_mfma_f32_16x16x32_bf16(ak[kk], bv, oc[ef], 0, 0, 0);
        }
    }
    float* so = states + (size_t)blockIdx.x * 4096;
    #pragma unroll
    for (int ef = 0; ef < 4; ++ef)
        #pragma unroll
        for (int r = 0; r < 4; ++r) {
            int dd = w * 16 + g * 4 + r;
            int e = ef * 16 + (lane & 15);
            so[dd * 64 + e] = oc[ef][r];
        }
    if (w == 0) {
        float s = ksumP[0][lane] + ksumP[1][lane] + ksumP[2][lane] + ksumP[3][lane];
        ksum[(size_t)blockIdx.x * 64 + lane] = s;
    }
}

// ---------------- attention pass B: exclusive prefix over chunks ----------------
__global__ __launch_bounds__(256)
void attn_prefix(const float* __restrict__ states, const float* __restrict__ ksum,
                 float* __restrict__ sprefix, float* __restrict__ kprefix) {
    const int bh = blockIdx.x >> 4;
    const int idx = (blockIdx.x & 15) * 256 + threadIdx.x;
    size_t base = (size_t)bh * NCH * 4096 + idx;
    float run = 0.f;
    #pragma unroll 4
    for (int cc = 0; cc < NCH; ++cc) {
        size_t o = base + (size_t)cc * 4096;
        float v = states[o];
        sprefix[o] = run;
        run += v;
    }
    if ((blockIdx.x & 15) == 0 && threadIdx.x < 64) {
        size_t kb = (size_t)bh * NCH * 64 + threadIdx.x;
        float krun = 0.f;
        for (int cc = 0; cc < NCH; ++cc) {
            size_t o = kb + (size_t)cc * 64;
            float v = ksum[o];
            kprefix[o] = krun;
            krun += v;
        }
    }
}

// ---------------- attention pass C (MFMA): intra + inter, write bf16 ----------------
__global__ __launch_bounds__(256)
void attn_output(const float* __restrict__ qkv, const int* __restrict__ len,
                 const float* __restrict__ sprefix, const float* __restrict__ kprefix,
                 unsigned short* __restrict__ a_bf) {
    const int c = blockIdx.x & (NCH - 1);
    const int bh = blockIdx.x / NCH;
    const int b = bh >> 3, h = bh & 7;
    const int L = len[b];
    const int tid = threadIdx.x;
    const int w = tid >> 6, lane = tid & 63;

    __shared__ __align__(16) unsigned short Qb[64 * 64];    // [i][d] swizzled
    __shared__ __align__(16) unsigned short Kb[64 * 64];    // [j][d] swizzled; reused for out
    __shared__ __align__(16) unsigned short SpT[64 * 64];   // [e][d] swizzled
    __shared__ __align__(16) unsigned short Vt[64 * 64];    // [e][j] swizzled
    __shared__ __align__(16) unsigned short Amb[64 * 64];   // [i][j] swizzled
    __shared__ float zq[64];
    __shared__ float zinv[64];

    const float kspv = kprefix[(size_t)(bh * NCH + c) * 64 + lane];
    const float* Sp = sprefix + (size_t)(bh * NCH + c) * 4096;

    #pragma unroll 4
    for (int t = 0; t < 16; ++t) {
        const int jj = 4 * t + w;
        const int d = lane;
        const int sglob = c * 64 + jj;
        const float* base = qkv + (size_t)(b * SS + sglob) * 1536 + h * 64 + d;
        float qv = base[0], kv = base[512], vv = base[1024];
        float qp = phi_f(qv);
        float kp = (sglob < L) ? phi_f(kv) : 0.f;
        const int swr = (((d >> 3) ^ (jj & 7)) << 3) + (d & 7);   // row-major (jj, d)
        Qb[jj * 64 + swr] = f2bf(qp);
        Kb[jj * 64 + swr] = f2bf(kp);
        const int swt = (((jj >> 3) ^ (d & 7)) << 3) + (jj & 7);  // transposed (d, jj)
        Vt[d * 64 + swt] = f2bf(vv);
        float spv = Sp[jj * 64 + d];                              // Sp[dstate=jj][e=d]
        SpT[d * 64 + swt] = f2bf(spv);
        float zc = qp * kspv;                                     // Q . kprefix
        #pragma unroll
        for (int off = 32; off; off >>= 1) zc += __shfl_xor(zc, off);
        if (lane == 0) zq[jj] = zc;
    }
    __syncthreads();

    const int frow = w * 16 + (lane & 15);
    const int g = lane >> 4;
    bf16x8 aq[2];
    #pragma unroll
    for (int kk = 0; kk < 2; ++kk)
        aq[kk] = *(const bf16x8*)&Qb[frow * 64 + (((kk * 4 + g) ^ (frow & 7)) << 3)];

    // phase 1: Am = Q K^T
    f32x4 am[4] = {};
    #pragma unroll
    for (int jf = 0; jf < 4; ++jf) {
        int brow = jf * 16 + (lane & 15);
        #pragma unroll
        for (int kk = 0; kk < 2; ++kk) {
            bf16x8 bk = *(const bf16x8*)&Kb[brow * 64 + (((kk * 4 + g) ^ (brow & 7)) << 3)];
            am[jf] = __builtin_amdgcn_mfma_f32_16x16x32_bf16(aq[kk], bk, am[jf], 0, 0, 0);
        }
    }

    // phase 2: mask, z row-sums, Amb store (bf16)
    float zl[4] = {0.f, 0.f, 0.f, 0.f};
    #pragma unroll
    for (int jf = 0; jf < 4; ++jf) {
        #pragma unroll
        for (int r = 0; r < 4; ++r) {
            int i = w * 16 + g * 4 + r;
            int j = jf * 16 + (lane & 15);
            float v = (j <= i) ? am[jf][r] : 0.f;
            zl[r] += v;
            Amb[i * 64 + (((j >> 3) ^ (i & 7)) << 3) + (j & 7)] = f2bf(v);
        }
    }
    #pragma unroll
    for (int r = 0; r < 4; ++r)
        #pragma unroll
        for (int off = 1; off < 16; off <<= 1) zl[r] += __shfl_xor(zl[r], off);
    #pragma unroll
    for (int r = 0; r < 4; ++r) {
        if ((lane & 15) == r) {
            int i = w * 16 + g * 4 + r;
            zinv[i] = 1.f / (zl[r] + zq[i] + ATT_EPS);
        }
    }

    // phase 4: out = Q*SpT^T + Am*Vt^T
    f32x4 oc[4] = {};
    #pragma unroll
    for (int ef = 0; ef < 4; ++ef) {
        int brow = ef * 16 + (lane & 15);
        #pragma unroll
        for (int kk = 0; kk < 2; ++kk) {
            bf16x8 bs = *(const bf16x8*)&SpT[brow * 64 + (((kk * 4 + g) ^ (brow & 7)) << 3)];
            oc[ef] = __builtin_amdgcn_mfma_f32_16x16x32_bf16(aq[kk], bs, oc[ef], 0, 0, 0);
        }
    }
    bf16x8 aam[2];
    #pragma unroll
    for (int kk = 0; kk < 2; ++kk)
        aam[kk] = *(const bf16x8*)&Amb[frow * 64 + (((kk * 4 + g) ^ (frow & 7)) << 3)];
    #pragma unroll
    for (int ef = 0; ef < 4; ++ef) {
        int brow = ef * 16 + (lane & 15);
        #pragma unroll
        for (int kk = 0; kk < 2; ++kk) {
            bf16x8 bv = *(const bf16x8*)&Vt[brow * 64 + (((kk * 4 + g) ^ (brow & 7)) << 3)];
            oc[ef] = __builtin_amdgcn_mfma_f32_16x16x32_bf16(aam[kk], bv, oc[ef], 0, 0, 0);
        }
    }

    __syncthreads();   // all waves done reading Kb -> reuse as out staging
    #pragma unroll
    for (int ef = 0; ef < 4; ++ef) {
        #pragma unroll
        for (int r = 0; r < 4; ++r) {
            int i = w * 16 + g * 4 + r;
            int e = ef * 16 + (lane & 15);
            float zi = zinv[i];
            Kb[i * 64 + (((e >> 3) ^ (i & 7)) << 3) + (e & 7)] = f2bf(oc[ef][r] * zi);
        }
    }
    __syncthreads();
    {
        unsigned short* dst = a_bf + (size_t)(b * SS + c * 64) * 512 + h * 64;
        #pragma unroll
        for (int u = 0; u < 2; ++u) {
            int cid = tid + u * 256;            // chunk id 0..511
            int row = cid >> 3, cb = cid & 7;
            int4 val = *(const int4*)&Kb[row * 64 + ((cb ^ (row & 7)) << 3)];
            *(int4*)(dst + (size_t)row * 512 + cb * 8) = val;
        }
    }
}

// ---------------- residual + LayerNorm (wave per row) ----------------
template<int ADD, int WB>
__global__ __launch_bounds__(64)
void ln_kernel(const float* __restrict__ hin, const float* __restrict__ add,
               const float* __restrict__ gw, const float* __restrict__ bw,
               float* __restrict__ hout, unsigned short* __restrict__ hbf) {
    const int row = blockIdx.x;
    const int lane = threadIdx.x;
    float v[8];
    const float* hp = hin + (size_t)row * DD;
    float s = 0.f;
    #pragma unroll
    for (int i = 0; i < 2; ++i) {
        int q = lane + i * 64;
        float4 a = ((const float4*)hp)[q];
        if (ADD) {
            float4 bb = ((const float4*)(add + (size_t)row * DD))[q];
            a.x += bb.x; a.y += bb.y; a.z += bb.z; a.w += bb.w;
        }
        v[i*4+0] = a.x; v[i*4+1] = a.y; v[i*4+2] = a.z; v[i*4+3] = a.w;
        s += a.x + a.y + a.z + a.w;
    }
    #pragma unroll
    for (int off = 32; off; off >>= 1) s += __shfl_xor(s, off);
    float mu = s * (1.f / 512.f);
    float sq = 0.f;
    #pragma unroll
    for (int i = 0; i < 8; ++i) { float d = v[i] - mu; sq += d * d; }
    #pragma unroll
    for (int off = 32; off; off >>= 1) sq += __shfl_xor(sq, off);
    float rs = 1.f / sqrtf(sq * (1.f / 512.f) + LN_EPS);
    #pragma unroll
    for (int i = 0; i < 2; ++i) {
        int q = lane + i * 64;
        float4 gv = ((const float4*)gw)[q];
        float4 bv = ((const float4*)bw)[q];
        float4 o;
        o.x = (v[i*4+0] - mu) * rs * gv.x + bv.x;
        o.y = (v[i*4+1] - mu) * rs * gv.y + bv.y;
        o.z = (v[i*4+2] - mu) * rs * gv.z + bv.z;
        o.w = (v[i*4+3] - mu) * rs * gv.w + bv.w;
        ((float4*)(hout + (size_t)row * DD))[q] = o;
        if (WB) {
            ushort4 ub; ub.x = f2bf(o.x); ub.y = f2bf(o.y); ub.z = f2bf(o.z); ub.w = f2bf(o.w);
            ((ushort4*)(hbf + (size_t)row * DD))[q] = ub;
        }
    }
}

// ---------------- host ----------------
extern "C" void kernel_launch(void* const* d_in, const int* in_sizes, int n_in,
                              void* d_out, int out_size, void* d_ws, size_t ws_size,
                              hipStream_t stream) {
    (void)in_sizes; (void)n_in; (void)out_size; (void)ws_size;
    const int*   x   = (const int*)d_in[0];
    const float* emb = (const float*)d_in[1];
    const float* pe  = (const float*)d_in[2];
    const float* Wq  = (const float*)d_in[3];
    const float* bq  = (const float*)d_in[4];
    const float* Wk  = (const float*)d_in[5];
    const float* bk  = (const float*)d_in[6];
    const float* Wv  = (const float*)d_in[7];
    const float* bv  = (const float*)d_in[8];
    const float* Wo  = (const float*)d_in[9];
    const float* bo  = (const float*)d_in[10];
    const float* W1  = (const float*)d_in[11];
    const float* b1  = (const float*)d_in[12];
    const float* W2  = (const float*)d_in[13];
    const float* b2  = (const float*)d_in[14];
    const float* g1  = (const float*)d_in[15];
    const float* be1 = (const float*)d_in[16];
    const float* g2  = (const float*)d_in[17];
    const float* be2 = (const float*)d_in[18];
    const float* gf  = (const float*)d_in[19];
    const float* bff = (const float*)d_in[20];
    float* out = (float*)d_out;

    char* ws = (char*)d_ws;
    size_t off = 0;
    auto alloc = [&](size_t bytes) -> void* {
        void* p = ws + off; off += (bytes + 255) & ~(size_t)255; return p;
    };
    int* len              = (int*)alloc(16);
    unsigned short* qkv_t = (unsigned short*)alloc((size_t)NLAYER * 1536 * 512 * 2);
    unsigned short* wo_t  = (unsigned short*)alloc((size_t)NLAYER * 512 * 512 * 2);
    unsigned short* w1_t  = (unsigned short*)alloc((size_t)NLAYER * 2048 * 512 * 2);
    unsigned short* w2_t  = (unsigned short*)alloc((size_t)NLAYER * 512 * 2048 * 2);
    float* bqkv           = (float*)alloc((size_t)NLAYER * 1536 * 4);
    float* h              = (float*)alloc((size_t)TT * 512 * 4);
    unsigned short* h_bf  = (unsigned short*)alloc((size_t)TT * 512 * 2);
    float* qkv            = (float*)alloc((size_t)TT * 1536 * 4);
    unsigned short* a_bf  = (unsigned short*)alloc((size_t)TT * 512 * 2);
    float* obuf           = (float*)alloc((size_t)TT * 512 * 4);
    unsigned short* y1_bf = (unsigned short*)alloc((size_t)TT * 2048 * 2);
    float* states         = (float*)alloc((size_t)32 * NCH * 4096 * 4);
    float* ksum           = (float*)alloc((size_t)32 * NCH * 64 * 4);
    float* sprefix        = (float*)alloc((size_t)32 * NCH * 4096 * 4);
    float* kprefix        = (float*)alloc((size_t)32 * NCH * 64 * 4);

    len_kernel<<<BB, 64, 0, stream>>>(x, len);
    embed_kernel<<<(TT * 128) / 256, 256, 0, stream>>>(x, emb, pe, h, h_bf);

    dim3 tb(256);
    transpose_cvt<<<dim3(16, 16, NLAYER), tb, 0, stream>>>(Wq, qkv_t,             512, 512, (size_t)512*512, (size_t)1536*512);
    transpose_cvt<<<dim3(16, 16, NLAYER), tb, 0, stream>>>(Wk, qkv_t + 512*512,   512, 512, (size_t)512*512, (size_t)1536*512);
    transpose_cvt<<<dim3(16, 16, NLAYER), tb, 0, stream>>>(Wv, qkv_t + 1024*512,  512, 512, (size_t)512*512, (size_t)1536*512);
    transpose_cvt<<<dim3(16, 16, NLAYER), tb, 0, stream>>>(Wo, wo_t,              512, 512, (size_t)512*512, (size_t)512*512);
    transpose_cvt<<<dim3(64, 16, NLAYER), tb, 0, stream>>>(W1, w1_t,              512, 2048, (size_t)512*2048, (size_t)2048*512);
    transpose_cvt<<<dim3(16, 64, NLAYER), tb, 0, stream>>>(W2, w2_t,              2048, 512, (size_t)2048*512, (size_t)512*2048);
    bias_concat<<<(NLAYER * 1536 + 255) / 256, 256, 0, stream>>>(bq, bk, bv, bqkv);

    for (int l = 0; l < NLAYER; ++l) {
        gemm_bt<0,1,0><<<dim3(TT/128, 1536/128), 256, 0, stream>>>(
            h_bf, qkv_t + (size_t)l*1536*512, bqkv + l*1536, qkv, nullptr, TT, 1536, 512);
        attn_chunk_sums<<<32 * NCH, 256, 0, stream>>>(qkv, len, states, ksum);
        attn_prefix<<<32 * 16, 256, 0, stream>>>(states, ksum, sprefix, kprefix);
        attn_output<<<32 * NCH, 256, 0, stream>>>(qkv, len, sprefix, kprefix, a_bf);
        gemm_bt<0,1,0><<<dim3(TT/128, 512/128), 256, 0, stream>>>(
            a_bf, wo_t + (size_t)l*512*512, bo + l*512, obuf, nullptr, TT, 512, 512);
        ln_kernel<1,1><<<TT, 64, 0, stream>>>(h, obuf, g1 + l*512, be1 + l*512, h, h_bf);
        gemm_bt<1,0,1><<<dim3(TT/128, 2048/128), 256, 0, stream>>>(
            h_bf, w1_t + (size_t)l*2048*512, b1 + l*2048, nullptr, y1_bf, TT, 2048, 512);
        gemm_bt<0,1,0><<<dim3(TT/128, 512/128), 256, 0, stream>>>(
            y1_bf, w2_t + (size_t)l*512*2048, b2 + l*512, obuf, nullptr, TT, 512, 2048);
        ln_kernel<1,1><<<TT, 64, 0, stream>>>(h, obuf, g2 + l*512, be2 + l*512, h, h_bf);
    }
    ln_kernel<0,0><<<TT, 64, 0, stream>>>(h, nullptr, gf, bff, out, nullptr);
}

// Round 4
// 594.520 us; speedup vs baseline: 1.5922x; 1.0914x over previous
//
#include <hip/hip_runtime.h>
#include <math.h>

#define NLAYER 4
#define BB 4
#define SS 2048
#define DD 512
#define HH 8
#define DH 64
#define FF 2048
#define TT (BB*SS)      // 8192 tokens
#define LCH 64          // attention chunk length
#define NCH (SS/LCH)    // 32 chunks
#define LN_EPS 1e-5f
#define ATT_EPS 1e-6f

typedef __bf16 bf16x8 __attribute__((ext_vector_type(8)));
typedef float  f32x4  __attribute__((ext_vector_type(4)));

__device__ __forceinline__ unsigned short f2bf(float f) {
    union { float f; unsigned u; } a; a.f = f;
    unsigned u = a.u;
    unsigned r = (u + 0x7FFFu + ((u >> 16) & 1u)) >> 16;   // RNE
    return (unsigned short)r;
}
__device__ __forceinline__ float bf2f(unsigned short s) {
    union { unsigned u; float f; } a; a.u = ((unsigned)s) << 16;
    return a.f;
}
__device__ __forceinline__ float phi_f(float u) {   // elu(u)+1
    return u > 0.f ? u + 1.f : __expf(u);
}

// ---------------- lengths ----------------
__global__ __launch_bounds__(64)
void len_kernel(const int* __restrict__ x, int* __restrict__ len) {
    const int b = blockIdx.x;
    int cnt = 0;
    for (int s = threadIdx.x; s < SS; s += 64) cnt += (x[b * SS + s] != 0);
    #pragma unroll
    for (int off = 32; off; off >>= 1) cnt += __shfl_xor(cnt, off);
    if (threadIdx.x == 0) len[b] = cnt;
}

// ---------------- embedding + positional ----------------
__global__ __launch_bounds__(256)
void embed_kernel(const int* __restrict__ x, const float* __restrict__ emb,
                  const float* __restrict__ pe, float* __restrict__ h,
                  unsigned short* __restrict__ h_bf) {
    int t = blockIdx.x * 256 + threadIdx.x;   // over TT*128 float4 slots
    int row = t >> 7;
    int q = t & 127;
    int tok = x[row];
    int s = row & (SS - 1);
    float4 e = ((const float4*)(emb + (size_t)tok * DD))[q];
    float4 p = ((const float4*)(pe + (size_t)s * DD))[q];
    float4 v; v.x = e.x + p.x; v.y = e.y + p.y; v.z = e.z + p.z; v.w = e.w + p.w;
    ((float4*)(h + (size_t)row * DD))[q] = v;
    ushort4 ub; ub.x = f2bf(v.x); ub.y = f2bf(v.y); ub.z = f2bf(v.z); ub.w = f2bf(v.w);
    ((ushort4*)(h_bf + (size_t)row * DD))[q] = ub;
}

// ---------------- transpose f32[R][C] -> bf16[C][R] ----------------
__global__ __launch_bounds__(256)
void transpose_cvt(const float* __restrict__ src, unsigned short* __restrict__ dst,
                   int R, int C, size_t srcLS, size_t dstLS) {
    __shared__ float tile[32][33];
    const int z = blockIdx.z;
    src += (size_t)z * srcLS;
    dst += (size_t)z * dstLS;
    const int c0 = blockIdx.x * 32, r0 = blockIdx.y * 32;
    const int tx = threadIdx.x & 31, ty = threadIdx.x >> 5;  // ty 0..7
    #pragma unroll
    for (int i = 0; i < 32; i += 8)
        tile[ty + i][tx] = src[(size_t)(r0 + ty + i) * C + c0 + tx];
    __syncthreads();
    #pragma unroll
    for (int i = 0; i < 32; i += 8)
        dst[(size_t)(c0 + ty + i) * R + r0 + tx] = f2bf(tile[tx][ty + i]);
}

__global__ __launch_bounds__(256)
void bias_concat(const float* __restrict__ bq, const float* __restrict__ bk,
                 const float* __restrict__ bv, float* __restrict__ bqkv) {
    int idx = blockIdx.x * 256 + threadIdx.x;
    if (idx >= NLAYER * 1536) return;
    int l = idx / 1536, n = idx % 1536;
    float v = n < 512 ? bq[l * 512 + n] : (n < 1024 ? bk[l * 512 + n - 512] : bv[l * 512 + n - 1024]);
    bqkv[idx] = v;
}

// ---------------- bf16 MFMA GEMM:  C[M,N] = A[M,K] * Bt[N,K]^T + bias ----------------
__device__ __forceinline__ void gll16(void* lds_ptr, const void* g_ptr) {
    __builtin_amdgcn_global_load_lds(
        (const __attribute__((address_space(1))) void*)g_ptr,
        (__attribute__((address_space(3))) void*)lds_ptr, 16, 0, 0);
}

// 1-D grid = Mt*Nt blocks (divisible by 8), XCD-chunked swizzle: each XCD gets
// a contiguous 8-M-tile stripe across all N (n-fastest within chunk).
template<int RELU, int WF, int WB>
__global__ __launch_bounds__(256, 2)
void gemm_bt(const unsigned short* __restrict__ A, const unsigned short* __restrict__ Bt,
             const float* __restrict__ bias, float* __restrict__ Cf,
             unsigned short* __restrict__ Cb, int M, int N, int K) {
    __shared__ __align__(16) char lds[2 * 2 * 128 * 64 * 2];   // 64 KiB
    const int Nt = N >> 7;
    const int bid = blockIdx.x;
    const int swz = (bid & 7) * ((int)gridDim.x >> 3) + (bid >> 3);
    const int m0 = (swz / Nt) * 128;
    const int n0 = (swz % Nt) * 128;
    const int tid = threadIdx.x;
    const int w = tid >> 6, lane = tid & 63;
    const int wr = w >> 1, wc = w & 1;
    const int srow = lane >> 3, scc = lane & 7;

    f32x4 acc[4][4] = {};

    auto stage = [&](int buf, int k0) {
        char* base = lds + buf * 32768;
        #pragma unroll
        for (int op = 0; op < 2; ++op) {
            const unsigned short* G = op ? Bt : A;
            const int r0 = op ? n0 : m0;
            char* obase = base + op * 16384;
            #pragma unroll
            for (int i = 0; i < 4; ++i) {
                int ii = w * 4 + i;
                int row = ii * 8 + srow;                 // row within tile
                int chunk = scc ^ (row & 7);             // pre-swizzled global source
                gll16(obase + ii * 1024,
                      G + (size_t)(r0 + row) * K + k0 + chunk * 8);
            }
        }
    };

    stage(0, 0);
    const int nt = K >> 6;
    int buf = 0;
    const int g = lane >> 4;
    const int rA = wr * 64 + (lane & 15);
    const int rB = wc * 64 + (lane & 15);

    for (int kt = 0; kt < nt; ++kt) {
        __syncthreads();
        if (kt + 1 < nt) stage(buf ^ 1, (kt + 1) << 6);
        const char* pA = lds + buf * 32768;
        const char* pB = pA + 16384;
        bf16x8 af[4][2], bfr[4][2];
        #pragma unroll
        for (int m = 0; m < 4; ++m)
            #pragma unroll
            for (int kk = 0; kk < 2; ++kk) {
                int row = rA + m * 16;
                int c = (kk * 4 + g) ^ (row & 7);
                af[m][kk] = *(const bf16x8*)(pA + row * 128 + c * 16);
            }
        #pragma unroll
        for (int n = 0; n < 4; ++n)
            #pragma unroll
            for (int kk = 0; kk < 2; ++kk) {
                int row = rB + n * 16;
                int c = (kk * 4 + g) ^ (row & 7);
                bfr[n][kk] = *(const bf16x8*)(pB + row * 128 + c * 16);
            }
        #pragma unroll
        for (int kk = 0; kk < 2; ++kk)
            #pragma unroll
            for (int m = 0; m < 4; ++m)
                #pragma unroll
                for (int n = 0; n < 4; ++n)
                    acc[m][n] = __builtin_amdgcn_mfma_f32_16x16x32_bf16(
                        af[m][kk], bfr[n][kk], acc[m][n], 0, 0, 0);
        buf ^= 1;
    }

    const int col16 = lane & 15;
    const int rgrp = lane >> 4;
    #pragma unroll
    for (int n = 0; n < 4; ++n) {
        int col = n0 + wc * 64 + n * 16 + col16;
        float bi = bias[col];
        #pragma unroll
        for (int m = 0; m < 4; ++m) {
            int rowb = m0 + wr * 64 + m * 16 + rgrp * 4;
            #pragma unroll
            for (int r = 0; r < 4; ++r) {
                float v = acc[m][n][r] + bi;
                if (RELU) v = v > 0.f ? v : 0.f;
                if (WF) Cf[(size_t)(rowb + r) * N + col] = v;
                if (WB) Cb[(size_t)(rowb + r) * N + col] = f2bf(v);
            }
        }
    }
}

// ---------------- attention pass A (MFMA): states = K^T V (bf16 out), ksum ----------------
__global__ __launch_bounds__(256)
void attn_chunk_sums(const unsigned short* __restrict__ qkv, const int* __restrict__ len,
                     unsigned short* __restrict__ states, float* __restrict__ ksum) {
    const int c = blockIdx.x & (NCH - 1);
    const int bh = blockIdx.x / NCH;
    const int b = bh >> 3, h = bh & 7;
    const int L = len[b];
    const int tid = threadIdx.x;
    const int w = tid >> 6, lane = tid & 63;
    __shared__ __align__(16) unsigned short Kt[64 * 64];   // [d][j], swizzled
    __shared__ __align__(16) unsigned short Vt[64 * 64];   // [e][j], swizzled
    __shared__ float ksumP[4][64];

    float kpart = 0.f;
    #pragma unroll 8
    for (int t = 0; t < 16; ++t) {
        const int jj = 4 * t + w;
        const int d = lane;
        const int sglob = c * 64 + jj;
        const unsigned short* base = qkv + (size_t)(b * SS + sglob) * 1536 + h * 64 + d;
        float kv = bf2f(base[512]);
        float kp = (sglob < L) ? phi_f(kv) : 0.f;
        kpart += kp;
        const int sw = (((jj >> 3) ^ (d & 7)) << 3) + (jj & 7);
        Kt[d * 64 + sw] = f2bf(kp);
        Vt[d * 64 + sw] = base[1024];
    }
    ksumP[w][lane] = kpart;
    __syncthreads();

    const int frow = w * 16 + (lane & 15);   // d-row of output
    const int g = lane >> 4;
    bf16x8 ak[2];
    #pragma unroll
    for (int kk = 0; kk < 2; ++kk)
        ak[kk] = *(const bf16x8*)&Kt[frow * 64 + (((kk * 4 + g) ^ (frow & 7)) << 3)];
    f32x4 oc[4] = {};
    #pragma unroll
    for (int ef = 0; ef < 4; ++ef) {
        int brow = ef * 16 + (lane & 15);
        #pragma unroll
        for (int kk = 0; kk < 2; ++kk) {
            bf16x8 bv = *(const bf16x8*)&Vt[brow * 64 + (((kk * 4 + g) ^ (brow & 7)) << 3)];
            oc[ef] = __builtin_amdgcn_mfma_f32_16x16x32_bf16(ak[kk], bv, oc[ef], 0, 0, 0);
        }
    }
    unsigned short* so = states + (size_t)blockIdx.x * 4096;
    #pragma unroll
    for (int ef = 0; ef < 4; ++ef)
        #pragma unroll
        for (int r = 0; r < 4; ++r) {
            int dd = w * 16 + g * 4 + r;
            int e = ef * 16 + (lane & 15);
            so[dd * 64 + e] = f2bf(oc[ef][r]);
        }
    if (w == 0) {
        float s = ksumP[0][lane] + ksumP[1][lane] + ksumP[2][lane] + ksumP[3][lane];
        ksum[(size_t)blockIdx.x * 64 + lane] = s;
    }
}

// ---------------- attention pass B: exclusive prefix over chunks (bf16 in/out) ----------------
__global__ __launch_bounds__(256)
void attn_prefix(const unsigned short* __restrict__ states, const float* __restrict__ ksum,
                 unsigned short* __restrict__ sprefix, float* __restrict__ kprefix) {
    const int bh = blockIdx.x >> 4;
    const int idx = (blockIdx.x & 15) * 256 + threadIdx.x;
    size_t base = (size_t)bh * NCH * 4096 + idx;
    float run = 0.f;
    #pragma unroll 4
    for (int cc = 0; cc < NCH; ++cc) {
        size_t o = base + (size_t)cc * 4096;
        float v = bf2f(states[o]);
        sprefix[o] = f2bf(run);
        run += v;
    }
    if ((blockIdx.x & 15) == 0 && threadIdx.x < 64) {
        size_t kb = (size_t)bh * NCH * 64 + threadIdx.x;
        float krun = 0.f;
        for (int cc = 0; cc < NCH; ++cc) {
            size_t o = kb + (size_t)cc * 64;
            float v = ksum[o];
            kprefix[o] = krun;
            krun += v;
        }
    }
}

// ---------------- attention pass C (MFMA): intra + inter, write bf16 ----------------
__global__ __launch_bounds__(256)
void attn_output(const unsigned short* __restrict__ qkv, const int* __restrict__ len,
                 const unsigned short* __restrict__ sprefix, const float* __restrict__ kprefix,
                 unsigned short* __restrict__ a_bf) {
    const int c = blockIdx.x & (NCH - 1);
    const int bh = blockIdx.x / NCH;
    const int b = bh >> 3, h = bh & 7;
    const int L = len[b];
    const int tid = threadIdx.x;
    const int w = tid >> 6, lane = tid & 63;

    __shared__ __align__(16) unsigned short Qb[64 * 64];    // [i][d] swizzled
    __shared__ __align__(16) unsigned short Kb[64 * 64];    // [j][d] swizzled; reused for out
    __shared__ __align__(16) unsigned short SpT[64 * 64];   // [e][d] swizzled
    __shared__ __align__(16) unsigned short Vt[64 * 64];    // [e][j] swizzled
    __shared__ __align__(16) unsigned short Amb[64 * 64];   // [i][j] swizzled
    __shared__ float zq[64];
    __shared__ float zinv[64];

    const float kspv = kprefix[(size_t)(bh * NCH + c) * 64 + lane];
    const unsigned short* Sp = sprefix + (size_t)(bh * NCH + c) * 4096;

    #pragma unroll 4
    for (int t = 0; t < 16; ++t) {
        const int jj = 4 * t + w;
        const int d = lane;
        const int sglob = c * 64 + jj;
        const unsigned short* base = qkv + (size_t)(b * SS + sglob) * 1536 + h * 64 + d;
        float qv = bf2f(base[0]), kv = bf2f(base[512]);
        float qp = phi_f(qv);
        float kp = (sglob < L) ? phi_f(kv) : 0.f;
        const int swr = (((d >> 3) ^ (jj & 7)) << 3) + (d & 7);   // row-major (jj, d)
        Qb[jj * 64 + swr] = f2bf(qp);
        Kb[jj * 64 + swr] = f2bf(kp);
        const int swt = (((jj >> 3) ^ (d & 7)) << 3) + (jj & 7);  // transposed (d, jj)
        Vt[d * 64 + swt] = base[1024];
        SpT[d * 64 + swt] = Sp[jj * 64 + d];                      // Sp[dstate=jj][e=d]
        float zc = qp * kspv;                                     // Q . kprefix
        #pragma unroll
        for (int off = 32; off; off >>= 1) zc += __shfl_xor(zc, off);
        if (lane == 0) zq[jj] = zc;
    }
    __syncthreads();

    const int frow = w * 16 + (lane & 15);
    const int g = lane >> 4;
    bf16x8 aq[2];
    #pragma unroll
    for (int kk = 0; kk < 2; ++kk)
        aq[kk] = *(const bf16x8*)&Qb[frow * 64 + (((kk * 4 + g) ^ (frow & 7)) << 3)];

    // phase 1: Am = Q K^T
    f32x4 am[4] = {};
    #pragma unroll
    for (int jf = 0; jf < 4; ++jf) {
        int brow = jf * 16 + (lane & 15);
        #pragma unroll
        for (int kk = 0; kk < 2; ++kk) {
            bf16x8 bk = *(const bf16x8*)&Kb[brow * 64 + (((kk * 4 + g) ^ (brow & 7)) << 3)];
            am[jf] = __builtin_amdgcn_mfma_f32_16x16x32_bf16(aq[kk], bk, am[jf], 0, 0, 0);
        }
    }

    // phase 2: mask, z row-sums, Amb store (bf16)
    float zl[4] = {0.f, 0.f, 0.f, 0.f};
    #pragma unroll
    for (int jf = 0; jf < 4; ++jf) {
        #pragma unroll
        for (int r = 0; r < 4; ++r) {
            int i = w * 16 + g * 4 + r;
            int j = jf * 16 + (lane & 15);
            float v = (j <= i) ? am[jf][r] : 0.f;
            zl[r] += v;
            Amb[i * 64 + (((j >> 3) ^ (i & 7)) << 3) + (j & 7)] = f2bf(v);
        }
    }
    #pragma unroll
    for (int r = 0; r < 4; ++r)
        #pragma unroll
        for (int off = 1; off < 16; off <<= 1) zl[r] += __shfl_xor(zl[r], off);
    #pragma unroll
    for (int r = 0; r < 4; ++r) {
        if ((lane & 15) == r) {
            int i = w * 16 + g * 4 + r;
            zinv[i] = 1.f / (zl[r] + zq[i] + ATT_EPS);
        }
    }

    // phase 4: out = Q*SpT^T + Am*Vt^T
    f32x4 oc[4] = {};
    #pragma unroll
    for (int ef = 0; ef < 4; ++ef) {
        int brow = ef * 16 + (lane & 15);
        #pragma unroll
        for (int kk = 0; kk < 2; ++kk) {
            bf16x8 bs = *(const bf16x8*)&SpT[brow * 64 + (((kk * 4 + g) ^ (brow & 7)) << 3)];
            oc[ef] = __builtin_amdgcn_mfma_f32_16x16x32_bf16(aq[kk], bs, oc[ef], 0, 0, 0);
        }
    }
    bf16x8 aam[2];
    #pragma unroll
    for (int kk = 0; kk < 2; ++kk)
        aam[kk] = *(const bf16x8*)&Amb[frow * 64 + (((kk * 4 + g) ^ (frow & 7)) << 3)];
    #pragma unroll
    for (int ef = 0; ef < 4; ++ef) {
        int brow = ef * 16 + (lane & 15);
        #pragma unroll
        for (int kk = 0; kk < 2; ++kk) {
            bf16x8 bv = *(const bf16x8*)&Vt[brow * 64 + (((kk * 4 + g) ^ (brow & 7)) << 3)];
            oc[ef] = __builtin_amdgcn_mfma_f32_16x16x32_bf16(aam[kk], bv, oc[ef], 0, 0, 0);
        }
    }

    __syncthreads();   // all waves done reading Kb -> reuse as out staging
    #pragma unroll
    for (int ef = 0; ef < 4; ++ef) {
        #pragma unroll
        for (int r = 0; r < 4; ++r) {
            int i = w * 16 + g * 4 + r;
            int e = ef * 16 + (lane & 15);
            float zi = zinv[i];
            Kb[i * 64 + (((e >> 3) ^ (i & 7)) << 3) + (e & 7)] = f2bf(oc[ef][r] * zi);
        }
    }
    __syncthreads();
    {
        unsigned short* dst = a_bf + (size_t)(b * SS + c * 64) * 512 + h * 64;
        #pragma unroll
        for (int u = 0; u < 2; ++u) {
            int cid = tid + u * 256;            // chunk id 0..511
            int row = cid >> 3, cb = cid & 7;
            int4 val = *(const int4*)&Kb[row * 64 + ((cb ^ (row & 7)) << 3)];
            *(int4*)(dst + (size_t)row * 512 + cb * 8) = val;
        }
    }
}

// ---------------- residual + LayerNorm (wave per row) ----------------
template<int ADD, int WB>
__global__ __launch_bounds__(64)
void ln_kernel(const float* __restrict__ hin, const float* __restrict__ add,
               const float* __restrict__ gw, const float* __restrict__ bw,
               float* __restrict__ hout, unsigned short* __restrict__ hbf) {
    const int row = blockIdx.x;
    const int lane = threadIdx.x;
    float v[8];
    const float* hp = hin + (size_t)row * DD;
    float s = 0.f;
    #pragma unroll
    for (int i = 0; i < 2; ++i) {
        int q = lane + i * 64;
        float4 a = ((const float4*)hp)[q];
        if (ADD) {
            float4 bb = ((const float4*)(add + (size_t)row * DD))[q];
            a.x += bb.x; a.y += bb.y; a.z += bb.z; a.w += bb.w;
        }
        v[i*4+0] = a.x; v[i*4+1] = a.y; v[i*4+2] = a.z; v[i*4+3] = a.w;
        s += a.x + a.y + a.z + a.w;
    }
    #pragma unroll
    for (int off = 32; off; off >>= 1) s += __shfl_xor(s, off);
    float mu = s * (1.f / 512.f);
    float sq = 0.f;
    #pragma unroll
    for (int i = 0; i < 8; ++i) { float d = v[i] - mu; sq += d * d; }
    #pragma unroll
    for (int off = 32; off; off >>= 1) sq += __shfl_xor(sq, off);
    float rs = 1.f / sqrtf(sq * (1.f / 512.f) + LN_EPS);
    #pragma unroll
    for (int i = 0; i < 2; ++i) {
        int q = lane + i * 64;
        float4 gv = ((const float4*)gw)[q];
        float4 bv = ((const float4*)bw)[q];
        float4 o;
        o.x = (v[i*4+0] - mu) * rs * gv.x + bv.x;
        o.y = (v[i*4+1] - mu) * rs * gv.y + bv.y;
        o.z = (v[i*4+2] - mu) * rs * gv.z + bv.z;
        o.w = (v[i*4+3] - mu) * rs * gv.w + bv.w;
        ((float4*)(hout + (size_t)row * DD))[q] = o;
        if (WB) {
            ushort4 ub; ub.x = f2bf(o.x); ub.y = f2bf(o.y); ub.z = f2bf(o.z); ub.w = f2bf(o.w);
            ((ushort4*)(hbf + (size_t)row * DD))[q] = ub;
        }
    }
}

// ---------------- host ----------------
extern "C" void kernel_launch(void* const* d_in, const int* in_sizes, int n_in,
                              void* d_out, int out_size, void* d_ws, size_t ws_size,
                              hipStream_t stream) {
    (void)in_sizes; (void)n_in; (void)out_size; (void)ws_size;
    const int*   x   = (const int*)d_in[0];
    const float* emb = (const float*)d_in[1];
    const float* pe  = (const float*)d_in[2];
    const float* Wq  = (const float*)d_in[3];
    const float* bq  = (const float*)d_in[4];
    const float* Wk  = (const float*)d_in[5];
    const float* bk  = (const float*)d_in[6];
    const float* Wv  = (const float*)d_in[7];
    const float* bv  = (const float*)d_in[8];
    const float* Wo  = (const float*)d_in[9];
    const float* bo  = (const float*)d_in[10];
    const float* W1  = (const float*)d_in[11];
    const float* b1  = (const float*)d_in[12];
    const float* W2  = (const float*)d_in[13];
    const float* b2  = (const float*)d_in[14];
    const float* g1  = (const float*)d_in[15];
    const float* be1 = (const float*)d_in[16];
    const float* g2  = (const float*)d_in[17];
    const float* be2 = (const float*)d_in[18];
    const float* gf  = (const float*)d_in[19];
    const float* bff = (const float*)d_in[20];
    float* out = (float*)d_out;

    char* ws = (char*)d_ws;
    size_t off = 0;
    auto alloc = [&](size_t bytes) -> void* {
        void* p = ws + off; off += (bytes + 255) & ~(size_t)255; return p;
    };
    int* len              = (int*)alloc(16);
    unsigned short* qkv_t = (unsigned short*)alloc((size_t)NLAYER * 1536 * 512 * 2);
    unsigned short* wo_t  = (unsigned short*)alloc((size_t)NLAYER * 512 * 512 * 2);
    unsigned short* w1_t  = (unsigned short*)alloc((size_t)NLAYER * 2048 * 512 * 2);
    unsigned short* w2_t  = (unsigned short*)alloc((size_t)NLAYER * 512 * 2048 * 2);
    float* bqkv           = (float*)alloc((size_t)NLAYER * 1536 * 4);
    float* h              = (float*)alloc((size_t)TT * 512 * 4);
    unsigned short* h_bf  = (unsigned short*)alloc((size_t)TT * 512 * 2);
    unsigned short* qkv   = (unsigned short*)alloc((size_t)TT * 1536 * 2);
    unsigned short* a_bf  = (unsigned short*)alloc((size_t)TT * 512 * 2);
    float* obuf           = (float*)alloc((size_t)TT * 512 * 4);
    unsigned short* y1_bf = (unsigned short*)alloc((size_t)TT * 2048 * 2);
    unsigned short* states  = (unsigned short*)alloc((size_t)32 * NCH * 4096 * 2);
    float* ksum           = (float*)alloc((size_t)32 * NCH * 64 * 4);
    unsigned short* sprefix = (unsigned short*)alloc((size_t)32 * NCH * 4096 * 2);
    float* kprefix        = (float*)alloc((size_t)32 * NCH * 64 * 4);

    len_kernel<<<BB, 64, 0, stream>>>(x, len);
    embed_kernel<<<(TT * 128) / 256, 256, 0, stream>>>(x, emb, pe, h, h_bf);

    dim3 tb(256);
    transpose_cvt<<<dim3(16, 16, NLAYER), tb, 0, stream>>>(Wq, qkv_t,             512, 512, (size_t)512*512, (size_t)1536*512);
    transpose_cvt<<<dim3(16, 16, NLAYER), tb, 0, stream>>>(Wk, qkv_t + 512*512,   512, 512, (size_t)512*512, (size_t)1536*512);
    transpose_cvt<<<dim3(16, 16, NLAYER), tb, 0, stream>>>(Wv, qkv_t + 1024*512,  512, 512, (size_t)512*512, (size_t)1536*512);
    transpose_cvt<<<dim3(16, 16, NLAYER), tb, 0, stream>>>(Wo, wo_t,              512, 512, (size_t)512*512, (size_t)512*512);
    transpose_cvt<<<dim3(64, 16, NLAYER), tb, 0, stream>>>(W1, w1_t,              512, 2048, (size_t)512*2048, (size_t)2048*512);
    transpose_cvt<<<dim3(16, 64, NLAYER), tb, 0, stream>>>(W2, w2_t,              2048, 512, (size_t)2048*512, (size_t)512*2048);
    bias_concat<<<(NLAYER * 1536 + 255) / 256, 256, 0, stream>>>(bq, bk, bv, bqkv);

    for (int l = 0; l < NLAYER; ++l) {
        gemm_bt<0,0,1><<<(TT/128) * (1536/128), 256, 0, stream>>>(
            h_bf, qkv_t + (size_t)l*1536*512, bqkv + l*1536, nullptr, qkv, TT, 1536, 512);
        attn_chunk_sums<<<32 * NCH, 256, 0, stream>>>(qkv, len, states, ksum);
        attn_prefix<<<32 * 16, 256, 0, stream>>>(states, ksum, sprefix, kprefix);
        attn_output<<<32 * NCH, 256, 0, stream>>>(qkv, len, sprefix, kprefix, a_bf);
        gemm_bt<0,1,0><<<(TT/128) * (512/128), 256, 0, stream>>>(
            a_bf, wo_t + (size_t)l*512*512, bo + l*512, obuf, nullptr, TT, 512, 512);
        ln_kernel<1,1><<<TT, 64, 0, stream>>>(h, obuf, g1 + l*512, be1 + l*512, h, h_bf);
        gemm_bt<1,0,1><<<(TT/128) * (2048/128), 256, 0, stream>>>(
            h_bf, w1_t + (size_t)l*2048*512, b1 + l*2048, nullptr, y1_bf, TT, 2048, 512);
        gemm_bt<0,1,0><<<(TT/128) * (512/128), 256, 0, stream>>>(
            y1_bf, w2_t + (size_t)l*512*2048, b2 + l*512, obuf, nullptr, TT, 512, 2048);
        ln_kernel<1,1><<<TT, 64, 0, stream>>>(h, obuf, g2 + l*512, be2 + l*512, h, h_bf);
    }
    ln_kernel<0,0><<<TT, 64, 0, stream>>>(h, nullptr, gf, bff, out, nullptr);
}